// Round 15
// baseline (327.166 us; speedup 1.0000x reference)
//
#include <hip/hip_runtime.h>

typedef __bf16 bf16x8 __attribute__((ext_vector_type(8)));
typedef float f32x4 __attribute__((ext_vector_type(4)));
typedef unsigned short u16;

__device__ __forceinline__ u16 f2bf(float f){
  unsigned u = __builtin_bit_cast(unsigned, f);
  u += 0x7fffu + ((u>>16)&1u);
  return (u16)(u>>16);
}
__device__ __forceinline__ float bf2f(u16 h){
  unsigned u = ((unsigned)h)<<16; return __builtin_bit_cast(float,u);
}
__device__ __forceinline__ bf16x8 ld8(const u16* p){ return *(const bf16x8*)p; }
__device__ __forceinline__ f32x4 mfma16(bf16x8 a, bf16x8 b, f32x4 c){
  return __builtin_amdgcn_mfma_f32_16x16x32_bf16(a,b,c,0,0,0);
}
__device__ __forceinline__ void gl16(const u16* g, u16* l){
  __builtin_amdgcn_global_load_lds(
    (const __attribute__((address_space(1))) unsigned int*)g,
    (__attribute__((address_space(3))) unsigned int*)l, 16, 0, 0);
}
// pack 2 f32 -> 2 bf16 (RNE), lo=a hi=b
__device__ __forceinline__ unsigned cvtpk(float a, float b){
  unsigned r;
  asm("v_cvt_pk_bf16_f32 %0, %1, %2" : "=v"(r) : "v"(a), "v"(b));
  return r;
}

#define QSC 0.18033688f   /* 0.125 * log2(e), folded into stored Q */

// ---------------- fused input split: trg+src fp32 -> bf16 ----------------
__global__ __launch_bounds__(256) void k_split2(const float* __restrict__ a,
    const float* __restrict__ b, u16* __restrict__ da, u16* __restrict__ db, int n){
  const float* s = blockIdx.y ? b : a;
  u16* d = blockIdx.y ? db : da;
  int i = (blockIdx.x*256 + threadIdx.x)*4;
  const int stride = gridDim.x*256*4;
  for(; i<n; i+=stride){
    float4 v = *(const float4*)(s+i);
    ushort4 H = {f2bf(v.x),f2bf(v.y),f2bf(v.z),f2bf(v.w)};
    *(ushort4*)(d+i)=H;
  }
}

// ---------------- fused weight splits (6 tensors in one launch) ----------------
struct SplitW { const float* s[6]; u16* d[6]; int n[6]; };
__global__ __launch_bounds__(256) void k_splitw(SplitW P){
  const int y = blockIdx.y;
  const float* s = P.s[y]; u16* d = P.d[y]; const int n = P.n[y];
  int i = (blockIdx.x*256 + threadIdx.x)*4;
  const int stride = gridDim.x*256*4;
  for(; i<n; i+=stride){
    float4 v = *(const float4*)(s+i);
    ushort4 H = {f2bf(v.x),f2bf(v.y),f2bf(v.z),f2bf(v.w)};
    *(ushort4*)(d+i)=H;
  }
}

// ---------------- 1-term bf16 GEMM, BK=32, double-buffered (R10 structure) ----------------
// C[m,n] = sum_k A[m,k]*W[n,k] + bias.  EPI: 0 = fp32 out, 1 = bf16 out, 2 = relu+bf16 out
template<int EPI>
__global__ __launch_bounds__(256) void k_gemm(
  const u16* __restrict__ A, const u16* __restrict__ W,
  const float* __restrict__ bias, int M, int N, int K,
  float* __restrict__ Cf, u16* __restrict__ Oh)
{
  __shared__ __align__(16) u16 sA[2][128*32], sW[2][128*32];
  const int tid = threadIdx.x, w = tid>>6, l = tid&63;
  const int l15 = l&15, g = l>>4;
  const int gx = gridDim.x;
  const int bid = blockIdx.y*gx + blockIdx.x;
  const int nwg = gx*gridDim.y;
  const int wgid = (bid&7)*(nwg>>3) + (bid>>3);
  const int m0 = (wgid/gx)*128, n0 = (wgid%gx)*128;
  const int wr = (w>>1)*64, wc = (w&1)*64;
  f32x4 acc[4][4] = {};
  const int sr = l>>2, sslot = l&3;
  const int scol = 8*((sslot - (sr>>1)) & 3);
  int offA[4], offW[4];
  #pragma unroll
  for(int i=0;i<4;i++){ const int R = wr+i*16+l15; offA[i] = R*32 + ((g+(R>>1))&3)*8; }
  #pragma unroll
  for(int j=0;j<4;j++){ const int C = wc+j*16+l15; offW[j] = C*32 + ((g+(C>>1))&3)*8; }
  const u16* Ab = A + (long)m0*K + scol;
  const u16* Wb = W + (long)n0*K + scol;
  const int nk = K>>5;

#define G_STAGE(BUF, T) { \
    const int k0 = (T)<<5; \
    _Pragma("unroll") \
    for(int i=0;i<2;i++){ \
      const int rows = i*64 + w*16; \
      gl16(Ab + (long)(rows+sr)*K + k0, sA[BUF] + rows*32); \
      gl16(Wb + (long)(rows+sr)*K + k0, sW[BUF] + rows*32); \
    } }

#define G_STEP(CUR, T) { \
    if((T)+1 < nk) G_STAGE(CUR^1, (T)+1); \
    bf16x8 av[4], wv[4]; \
    _Pragma("unroll") for(int i=0;i<4;i++) av[i] = *(const bf16x8*)(sA[CUR]+offA[i]); \
    _Pragma("unroll") for(int j=0;j<4;j++) wv[j] = *(const bf16x8*)(sW[CUR]+offW[j]); \
    _Pragma("unroll") for(int j=0;j<4;j++){ \
      _Pragma("unroll") for(int i=0;i<4;i++) acc[i][j] = mfma16(av[i], wv[j], acc[i][j]); } \
    __syncthreads(); }

  G_STAGE(0,0); __syncthreads();
  for(int t=0;t<nk;t+=2){ G_STEP(0,t); G_STEP(1,t+1); }
#undef G_STAGE
#undef G_STEP

  #pragma unroll
  for(int i=0;i<4;i++){
    #pragma unroll
    for(int j=0;j<4;j++){
      const int col  = n0 + wc + j*16 + l15;
      const float bb = bias ? bias[col] : 0.f;
      const int rowb = m0 + wr + i*16 + g*4;
      #pragma unroll
      for(int jj=0;jj<4;jj++){
        float v = acc[i][j][jj] + bb;
        const int row = rowb + jj;
        if constexpr(EPI==0){ Cf[(long)row*N + col] = v; }
        else if constexpr(EPI==1){ Oh[(long)row*N + col] = f2bf(v); }
        else { Oh[(long)row*N + col] = f2bf(fmaxf(v,0.f)); }
      }
    }
  }
}

// ---------------- fused QKV projection, 2-phase BK=32 gl16 (R10, proven 69us) ----------------
// W = [wq;wk;wv] concat (N=1536). Q scaled by QSC; V written permuted
// [b,h,d, t64*64 + (s&15)*4 + (s>>4)]
__global__ __launch_bounds__(256) void k_qkv(
  const u16* __restrict__ trg_hi, const u16* __restrict__ src_hi,
  const u16* __restrict__ Wh,
  const float* __restrict__ bq, const float* __restrict__ bk, const float* __restrict__ bv,
  u16* __restrict__ Qb, u16* __restrict__ Kb, u16* __restrict__ Vt)
{
  __shared__ __align__(16) u16 sA[2][128*32], sW[2][128*32];
  const int tid = threadIdx.x, w = tid>>6, l = tid&63;
  const int l15 = l&15, g = l>>4;
  const int bid = blockIdx.x;                 // grid = 1536
  const int wgid = (bid&7)*192 + (bid>>3);
  const int m0 = (wgid/12)*128, n0 = (wgid%12)*128;
  const u16* A = (n0<512)? trg_hi : src_hi;
  const float* bp = (n0<512)? bq : (n0<1024? bk : bv);
  const int nb = (n0<512)? 0 : (n0<1024? 512 : 1024);
  const int wr = (w>>1)*64, wc = (w&1)*64;
  f32x4 acc[4][4] = {};
  const int sr = l>>2, sslot = l&3;
  const int scol = 8*((sslot - (sr>>1)) & 3);
  int offA[4], offW[4];
  #pragma unroll
  for(int i=0;i<4;i++){ const int R = wr+i*16+l15; offA[i] = R*32 + ((g+(R>>1))&3)*8; }
  #pragma unroll
  for(int j=0;j<4;j++){ const int C = wc+j*16+l15; offW[j] = C*32 + ((g+(C>>1))&3)*8; }
  const u16* Ab = A  + (long)m0*512 + scol;
  const u16* Wb = Wh + (long)n0*512 + scol;

#define Q_STAGE(BUF, T) { \
    const int k0 = (T)<<5; \
    _Pragma("unroll") \
    for(int i=0;i<2;i++){ \
      const int rows = i*64 + w*16; \
      gl16(Ab + (long)(rows+sr)*512 + k0, sA[BUF] + rows*32); \
      gl16(Wb + (long)(rows+sr)*512 + k0, sW[BUF] + rows*32); \
    } }

#define Q_STEP(CUR, T) { \
    if((T)+1 < 16) Q_STAGE(CUR^1, (T)+1); \
    bf16x8 av[4], wv[4]; \
    _Pragma("unroll") for(int i=0;i<4;i++) av[i] = *(const bf16x8*)(sA[CUR]+offA[i]); \
    _Pragma("unroll") for(int j=0;j<4;j++) wv[j] = *(const bf16x8*)(sW[CUR]+offW[j]); \
    _Pragma("unroll") for(int j=0;j<4;j++){ \
      _Pragma("unroll") for(int i=0;i<4;i++) acc[i][j] = mfma16(av[i], wv[j], acc[i][j]); } \
    __syncthreads(); }

  Q_STAGE(0,0); __syncthreads();
  for(int t=0;t<16;t+=2){ Q_STEP(0,t); Q_STEP(1,t+1); }
#undef Q_STAGE
#undef Q_STEP

  #pragma unroll
  for(int i=0;i<4;i++){
    #pragma unroll
    for(int j=0;j<4;j++){
      const int col = n0 + wc + j*16 + l15;
      const int cl  = col - nb;
      const float bb = bp[cl];
      const int rowb = m0 + wr + i*16 + g*4;
      #pragma unroll
      for(int jj=0;jj<4;jj++){
        float v = acc[i][j][jj] + bb;
        const int row = rowb + jj;
        if(n0 < 512){ Qb[(long)row*512 + cl] = f2bf(v*QSC); }
        else if(n0 < 1024){ Kb[(long)row*512 + cl] = f2bf(v); }
        else {
          const int h = cl>>6, d = cl&63;
          const long dst = (((long)(row>>10)*8 + h)*64 + d)*1024
                         + ((row>>6)&15)*64 + (row&15)*4 + ((row>>4)&3);
          Vt[dst] = f2bf(v);
        }
      }
    }
  }
}

// ---------------- flash attention (bf16), dh=64, QBLK=128, 8 waves (R10, proven) ----------------
__global__ __launch_bounds__(512) void k_attn(
  const u16* __restrict__ Q, const u16* __restrict__ K,
  const u16* __restrict__ Vt, u16* __restrict__ O)
{
  __shared__ __align__(16) u16 sK[64*64], sV[64*64];
  __shared__ __align__(16) u16 Ph[8][16*72];
  const int bid = blockIdx.x;                 // grid = 1024
  const int wg = (bid&7)*128 + (bid>>3);      // XCD-chunked
  const int q0 = (wg&7)*128, hd = (wg>>3)&7, b = wg>>6;
  const int tid = threadIdx.x, w = tid>>6, l = tid&63, l15 = l&15, g = l>>4;
  const int qrow = q0 + w*16 + l15;
  const long qoff = (long)(b*1024 + qrow)*512 + hd*64 + g*8;
  bf16x8 qf[2] = { ld8(Q+qoff), ld8(Q+qoff+32) };
  const int srw = l>>3, sslot = l&7;
  const int scol = 8*(sslot ^ srw);
  const int rows = w*8;                                // wave-uniform LDS base row
  const u16* Kb = K + (long)b*1024*512 + hd*64;        // [s][512]
  const u16* Vb = Vt + (long)(b*8+hd)*64*1024;         // [d][1024] (k'-permuted)
  f32x4 rs = {};
  f32x4 ctx[4] = {};
  for(int s0=0;s0<1024;s0+=64){
    gl16(Kb + (long)(s0+rows+srw)*512 + scol, sK + rows*64);
    gl16(Vb + (long)(rows+srw)*1024 + s0 + scol, sV + rows*64);
    __syncthreads();
    f32x4 sv[4];
    #pragma unroll
    for(int sf=0;sf<4;sf++){
      const int row = sf*16 + l15;
      f32x4 a = {};
      #pragma unroll
      for(int h=0;h<2;h++){
        const int ch = (g + 4*h) ^ (row&7);
        a = mfma16(qf[h], *(const bf16x8*)(sK + row*64 + ch*8), a);
      }
      sv[sf] = a;
    }
    float p[4][4];
    #pragma unroll
    for(int sf=0;sf<4;sf++){
      #pragma unroll
      for(int j=0;j<4;j++){
        p[sf][j] = exp2f(sv[sf][j]);
        rs[j] += p[sf][j];
      }
    }
    #pragma unroll
    for(int j=0;j<4;j++){
      uint2 pk = { cvtpk(p[0][j], p[1][j]), cvtpk(p[2][j], p[3][j]) };
      *(uint2*)(&Ph[w][(g*4+j)*72 + l15*4]) = pk;   // k' = l15*4 + sf
    }
    #pragma unroll
    for(int ss=0;ss<2;ss++){
      bf16x8 pa = *(const bf16x8*)(&Ph[w][l15*72 + ss*32 + g*8]);
      #pragma unroll
      for(int df=0;df<4;df++){
        const int row = df*16 + l15;
        const int ch = (ss*4 + g) ^ (row&7);
        ctx[df] = mfma16(pa, *(const bf16x8*)(sV + row*64 + ch*8), ctx[df]);
      }
    }
    __syncthreads();
  }
  float inv[4];
  #pragma unroll
  for(int j=0;j<4;j++){
    float t = rs[j];
    #pragma unroll
    for(int mask=1;mask<16;mask<<=1) t += __shfl_xor(t, mask);
    inv[j] = 1.f/t;
  }
  #pragma unroll
  for(int df=0;df<4;df++){
    #pragma unroll
    for(int j=0;j<4;j++){
      const float v = ctx[df][j] * inv[j];
      const long off = (long)(b*1024 + q0 + w*16 + g*4 + j)*512 + hd*64 + df*16 + l15;
      O[off] = f2bf(v);
    }
  }
}

// ---------------- fused residual + LayerNorm, bf16 i/o (one wave per row) ----------------
// XAF: 1 = xa is fp32 (trg input), 0 = xa is bf16. xb always bf16. Output bf16 (+norms).
template<int XAF>
__global__ __launch_bounds__(256) void k_ln(
  const float* __restrict__ xaf, const u16* __restrict__ xab,
  const u16* __restrict__ xbb,
  const float* __restrict__ gg, const float* __restrict__ bvec,
  u16* __restrict__ yh, float* __restrict__ norms)
{
  const int w = threadIdx.x>>6, l = threadIdx.x&63;
  const long rrow = (long)blockIdx.x*4 + w;
  const long base = rrow*512 + l*8;
  float va[8];
  if constexpr(XAF){
    float4 a0 = *(const float4*)(xaf+base), a1 = *(const float4*)(xaf+base+4);
    va[0]=a0.x; va[1]=a0.y; va[2]=a0.z; va[3]=a0.w;
    va[4]=a1.x; va[5]=a1.y; va[6]=a1.z; va[7]=a1.w;
  } else {
    ushort4 a0 = *(const ushort4*)(xab+base), a1 = *(const ushort4*)(xab+base+4);
    va[0]=bf2f(a0.x); va[1]=bf2f(a0.y); va[2]=bf2f(a0.z); va[3]=bf2f(a0.w);
    va[4]=bf2f(a1.x); va[5]=bf2f(a1.y); va[6]=bf2f(a1.z); va[7]=bf2f(a1.w);
  }
  ushort4 b0 = *(const ushort4*)(xbb+base), b1 = *(const ushort4*)(xbb+base+4);
  float v[8] = {va[0]+bf2f(b0.x), va[1]+bf2f(b0.y), va[2]+bf2f(b0.z), va[3]+bf2f(b0.w),
                va[4]+bf2f(b1.x), va[5]+bf2f(b1.y), va[6]+bf2f(b1.z), va[7]+bf2f(b1.w)};
  float s=0.f, q=0.f;
  #pragma unroll
  for(int j=0;j<8;j++){ s += v[j]; q += v[j]*v[j]; }
  #pragma unroll
  for(int mask=1;mask<64;mask<<=1){ s += __shfl_xor(s,mask); q += __shfl_xor(q,mask); }
  const float mu  = s*(1.f/512.f);
  const float var = q*(1.f/512.f) - mu*mu;
  const float rstd = rsqrtf(var + 1e-5f);
  float y[8]; float nq = 0.f;
  #pragma unroll
  for(int j=0;j<8;j++){
    const int c = l*8+j;
    y[j] = (v[j]-mu)*rstd*gg[c] + bvec[c];
    nq += y[j]*y[j];
  }
  u16 hv[8];
  #pragma unroll
  for(int j=0;j<8;j++){ hv[j]=f2bf(y[j]); }
  ushort4 hh0={hv[0],hv[1],hv[2],hv[3]}, hh1={hv[4],hv[5],hv[6],hv[7]};
  *(ushort4*)(yh+base)=hh0; *(ushort4*)(yh+base+4)=hh1;
  if(norms){
    #pragma unroll
    for(int mask=1;mask<64;mask<<=1) nq += __shfl_xor(nq,mask);
    if(l==0) norms[rrow] = sqrtf(nq);
  }
}

// ---------------- norm-softmax pooling, stage 1 (bf16 x2) ----------------
__global__ __launch_bounds__(256) void k_pool2(const u16* __restrict__ x2,
   const float* __restrict__ norms, float* __restrict__ partial)
{
  const int b = blockIdx.y, tc = blockIdx.z;
  const int col = blockIdx.x*256 + threadIdx.x;
  __shared__ float wsm[1024];
  __shared__ float red[4];
  const int tid = threadIdx.x, w = tid>>6, l = tid&63;
  float lm = -1e30f;
  for(int i=tid;i<1024;i+=256){ const float n = norms[b*1024+i]; wsm[i]=n; lm=fmaxf(lm,n); }
  #pragma unroll
  for(int mask=1;mask<64;mask<<=1) lm = fmaxf(lm, __shfl_xor(lm,mask));
  __syncthreads();
  if(l==0) red[w]=lm;
  __syncthreads();
  const float bm = fmaxf(fmaxf(red[0],red[1]), fmaxf(red[2],red[3]));
  __syncthreads();
  float ls = 0.f;
  for(int i=tid;i<1024;i+=256){ const float e = __expf(wsm[i]-bm); wsm[i]=e; ls+=e; }
  #pragma unroll
  for(int mask=1;mask<64;mask<<=1) ls += __shfl_xor(ls,mask);
  __syncthreads();
  if(l==0) red[w]=ls;
  __syncthreads();
  const float inv = 1.f/(red[0]+red[1]+red[2]+red[3]);
  float acc = 0.f;
  const int t0 = tc*128;
  for(int t=t0;t<t0+128;t++) acc += wsm[t]*bf2f(x2[((long)b*1024+t)*512 + col]);
  partial[((long)tc*16 + b)*512 + col] = acc*inv;
}

// ---------------- pooling, stage 2: fold 8 partials ----------------
__global__ __launch_bounds__(256) void k_poolr(const float* __restrict__ partial,
   float* __restrict__ pooled)
{
  const int i = blockIdx.x*256 + threadIdx.x;   // 8192 outputs
  float a = 0.f;
  #pragma unroll
  for(int tc=0;tc<8;tc++) a += partial[tc*8192 + i];
  pooled[i] = a;
}

// ---------------- classifier head (tiny) ----------------
__global__ __launch_bounds__(256) void k_head(const float* __restrict__ pooled,
  const float* __restrict__ w1, const float* __restrict__ b1,
  const float* __restrict__ w2, const float* __restrict__ b2,
  float* __restrict__ out)
{
  __shared__ float ps[16*512];
  __shared__ float h1[16*256];
  const int tid = threadIdx.x;
  for(int i=tid;i<16*512;i+=256) ps[i]=pooled[i];
  __syncthreads();
  float acc[16] = {};
  for(int k=0;k<512;k++){
    const float wv = w1[tid*512+k];
    #pragma unroll
    for(int i=0;i<16;i++) acc[i] += ps[i*512+k]*wv;
  }
  #pragma unroll
  for(int i=0;i<16;i++) h1[i*256+tid] = fmaxf(acc[i]+b1[tid], 0.f);
  __syncthreads();
  if(tid<32){
    const int i = tid>>1, o = tid&1;
    float a = b2[o];
    for(int k=0;k<256;k++) a += h1[i*256+k]*w2[o*256+k];
    out[i*2+o] = a;
  }
}

extern "C" void kernel_launch(void* const* d_in, const int* in_sizes, int n_in,
                              void* d_out, int out_size, void* d_ws, size_t ws_size,
                              hipStream_t stream)
{
  const float* trg  = (const float*)d_in[0];
  const float* src  = (const float*)d_in[1];
  const float* ln_g = (const float*)d_in[2];
  const float* ln_b = (const float*)d_in[3];
  const float* wq   = (const float*)d_in[4];  const float* bq  = (const float*)d_in[5];
  const float* wk   = (const float*)d_in[6];  const float* bk  = (const float*)d_in[7];
  const float* wv   = (const float*)d_in[8];  const float* bv  = (const float*)d_in[9];
  const float* wo   = (const float*)d_in[10]; const float* bo  = (const float*)d_in[11];
  const float* pf1w = (const float*)d_in[12]; const float* pf1b= (const float*)d_in[13];
  const float* pf2w = (const float*)d_in[14]; const float* pf2b= (const float*)d_in[15];
  const float* fc1w = (const float*)d_in[16]; const float* fc1b= (const float*)d_in[17];
  const float* fc2w = (const float*)d_in[18]; const float* fc2b= (const float*)d_in[19];
  float* out = (float*)d_out;

  // ---- workspace: 7 bf16 planes (112 MiB) + ~9 MiB weights/misc ----
  // liveness: split2{W:4,5} qkv{R:4,5 W:0,1,2} attn{R:0,1,2 W:3} wo{R:3 W:4}
  //           LN1{R:trg,4 W:5} ff1{R:5 W:0-3} ff2{R:0-3 W:4} LN2{R:5,4 W:6} pool{R:6}
  char* ws = (char*)d_ws;
  const size_t PL = (size_t)16384*512*2;          // one bf16 plane (16 MiB)
  auto P = [&](int i)->u16*{ return (u16*)(ws + (size_t)i*PL); };
  u16 *Qb=P(0), *Kb=P(1), *Vt=P(2), *ctx=P(3);
  u16 *trg_hi=P(4), *src_hi=P(5);                 // dead after qkv
  u16 *sa_bf = P(4);                              // wo out (over trg_hi), LN1 in
  u16 *x1_hi = P(5);                              // LN1 out (over src_hi); ff1 + LN2-residual in
  u16 *h_hi  = P(0);                              // planes 0-3 (64 MiB, over Q/K/V/ctx)
  u16 *ffb_bf= P(4);                              // ff2 out (over sa, dead after LN1)
  u16 *x2_bf = P(6);                              // LN2 out
  size_t off = 7*PL;
  auto carve = [&](size_t n)->char*{ char* p = ws+off; off += n; return p; };
  u16* wqkv_hi=(u16*)carve((size_t)1536*512*2);
  u16* wo_hi=(u16*)carve(512*512*2);
  u16* p1_hi=(u16*)carve((size_t)2048*512*2);
  u16* p2_hi=(u16*)carve((size_t)512*2048*2);
  float* norms  = (float*)carve(16384*4);
  float* partial= (float*)carve(8*16*512*4);
  float* pooled = (float*)carve(16*512*4);
  (void)ws_size; (void)in_sizes; (void)n_in; (void)out_size;

  const int NTOK = 16384;

  // input + weight splits (2 launches)
  k_split2<<<dim3(8192,2),256,0,stream>>>(trg, src, trg_hi, src_hi, NTOK*512);
  SplitW sw;
  sw.s[0]=wq;  sw.d[0]=wqkv_hi;           sw.n[0]=512*512;
  sw.s[1]=wk;  sw.d[1]=wqkv_hi+512*512;   sw.n[1]=512*512;
  sw.s[2]=wv;  sw.d[2]=wqkv_hi+1024*512;  sw.n[2]=512*512;
  sw.s[3]=wo;  sw.d[3]=wo_hi;             sw.n[3]=512*512;
  sw.s[4]=pf1w; sw.d[4]=p1_hi;            sw.n[4]=2048*512;
  sw.s[5]=pf2w; sw.d[5]=p2_hi;            sw.n[5]=512*2048;
  k_splitw<<<dim3(512,6),256,0,stream>>>(sw);

  // fused QKV projection (gl16 2-phase dbuf, R10-proven)
  k_qkv<<<dim3(1536),256,0,stream>>>(trg_hi,src_hi,wqkv_hi,bq,bk,bv,Qb,Kb,Vt);

  // attention (QBLK=128, 8 waves, shared single-buffer K/V)
  k_attn<<<dim3(1024),512,0,stream>>>(Qb,Kb,Vt,ctx);

  // output projection (bf16 out) + LN1 (bf16 out only)
  k_gemm<1><<<dim3(4,128),256,0,stream>>>(ctx,wo_hi,bo,NTOK,512,512,nullptr,sa_bf);
  k_ln<1><<<dim3(4096),256,0,stream>>>(trg, nullptr, sa_bf, ln_g, ln_b, x1_hi, nullptr);

  // FFN + LN2 (+ row norms); all bf16 intermediates
  k_gemm<2><<<dim3(16,128),256,0,stream>>>(x1_hi,p1_hi,pf1b,NTOK,2048,512,nullptr,h_hi);
  k_gemm<1><<<dim3(4,128),256,0,stream>>>(h_hi,p2_hi,pf2b,NTOK,512,2048,nullptr,ffb_bf);
  k_ln<0><<<dim3(4096),256,0,stream>>>(nullptr, x1_hi, ffb_bf, ln_g, ln_b, x2_bf, norms);

  // pooling (parallel 2-stage) + head
  k_pool2<<<dim3(2,16,8),256,0,stream>>>(x2_bf, norms, partial);
  k_poolr<<<dim3(32),256,0,stream>>>(partial, pooled);
  k_head<<<1,256,0,stream>>>(pooled, fc1w, fc1b, fc2w, fc2b, out);
}

// Round 16
// 318.257 us; speedup vs baseline: 1.0280x; 1.0280x over previous
//
#include <hip/hip_runtime.h>

typedef __bf16 bf16x8 __attribute__((ext_vector_type(8)));
typedef float f32x4 __attribute__((ext_vector_type(4)));
typedef unsigned short u16;

__device__ __forceinline__ u16 f2bf(float f){
  unsigned u = __builtin_bit_cast(unsigned, f);
  u += 0x7fffu + ((u>>16)&1u);
  return (u16)(u>>16);
}
__device__ __forceinline__ float bf2f(u16 h){
  unsigned u = ((unsigned)h)<<16; return __builtin_bit_cast(float,u);
}
__device__ __forceinline__ bf16x8 ld8(const u16* p){ return *(const bf16x8*)p; }
__device__ __forceinline__ f32x4 mfma16(bf16x8 a, bf16x8 b, f32x4 c){
  return __builtin_amdgcn_mfma_f32_16x16x32_bf16(a,b,c,0,0,0);
}
__device__ __forceinline__ void gl16(const u16* g, u16* l){
  __builtin_amdgcn_global_load_lds(
    (const __attribute__((address_space(1))) unsigned int*)g,
    (__attribute__((address_space(3))) unsigned int*)l, 16, 0, 0);
}
// pack 2 f32 -> 2 bf16 (RNE), lo=a hi=b
__device__ __forceinline__ unsigned cvtpk(float a, float b){
  unsigned r;
  asm("v_cvt_pk_bf16_f32 %0, %1, %2" : "=v"(r) : "v"(a), "v"(b));
  return r;
}

#define QSC 0.18033688f   /* 0.125 * log2(e), folded into stored Q */

// ---------------- fused input split: trg+src fp32 -> bf16 ----------------
__global__ __launch_bounds__(256) void k_split2(const float* __restrict__ a,
    const float* __restrict__ b, u16* __restrict__ da, u16* __restrict__ db, int n){
  const float* s = blockIdx.y ? b : a;
  u16* d = blockIdx.y ? db : da;
  int i = (blockIdx.x*256 + threadIdx.x)*4;
  const int stride = gridDim.x*256*4;
  for(; i<n; i+=stride){
    float4 v = *(const float4*)(s+i);
    ushort4 H = {f2bf(v.x),f2bf(v.y),f2bf(v.z),f2bf(v.w)};
    *(ushort4*)(d+i)=H;
  }
}

// ---------------- fused weight splits (6 tensors in one launch) ----------------
struct SplitW { const float* s[6]; u16* d[6]; int n[6]; };
__global__ __launch_bounds__(256) void k_splitw(SplitW P){
  const int y = blockIdx.y;
  const float* s = P.s[y]; u16* d = P.d[y]; const int n = P.n[y];
  int i = (blockIdx.x*256 + threadIdx.x)*4;
  const int stride = gridDim.x*256*4;
  for(; i<n; i+=stride){
    float4 v = *(const float4*)(s+i);
    ushort4 H = {f2bf(v.x),f2bf(v.y),f2bf(v.z),f2bf(v.w)};
    *(ushort4*)(d+i)=H;
  }
}

// ---------------- 1-term bf16 GEMM, BK=32, dbuf, 8 waves (64x32/wave) ----------------
// C[m,n] = sum_k A[m,k]*W[n,k] + bias.  EPI: 0 = fp32 out, 1 = bf16 out, 2 = relu+bf16 out
template<int EPI>
__global__ __launch_bounds__(512) void k_gemm(
  const u16* __restrict__ A, const u16* __restrict__ W,
  const float* __restrict__ bias, int M, int N, int K,
  float* __restrict__ Cf, u16* __restrict__ Oh)
{
  __shared__ __align__(16) u16 sA[2][128*32], sW[2][128*32];
  const int tid = threadIdx.x, w = tid>>6, l = tid&63;
  const int l15 = l&15, g = l>>4;
  const int gx = gridDim.x;
  const int bid = blockIdx.y*gx + blockIdx.x;
  const int nwg = gx*gridDim.y;
  const int wgid = (bid&7)*(nwg>>3) + (bid>>3);
  const int m0 = (wgid/gx)*128, n0 = (wgid%gx)*128;
  const int wm = w>>2, wn = w&3;            // 2x4 wave grid, 64x32 out each
  f32x4 acc[4][2] = {};
  const int lr = l>>2, lslot = l&3;         // staging: wave rows w*16..+16
  const int scol = 8*((lslot - ((lr>>1)&3)) & 3);
  const int wrow = w*16;
  int offA[4], offW[2];
  #pragma unroll
  for(int i=0;i<4;i++){ const int R = wm*64+i*16+l15; offA[i] = R*32 + ((g+(R>>1))&3)*8; }
  #pragma unroll
  for(int j=0;j<2;j++){ const int C = wn*32+j*16+l15; offW[j] = C*32 + ((g+(C>>1))&3)*8; }
  const u16* Ab = A + (long)m0*K + scol;
  const u16* Wb = W + (long)n0*K + scol;
  const int nk = K>>5;

#define G_STAGE(BUF, T) { \
    const int k0 = (T)<<5; \
    gl16(Ab + (long)(wrow+lr)*K + k0, sA[BUF] + wrow*32); \
    gl16(Wb + (long)(wrow+lr)*K + k0, sW[BUF] + wrow*32); }

#define G_STEP(CUR, T) { \
    if((T)+1 < nk) G_STAGE(CUR^1, (T)+1); \
    bf16x8 av[4], wv[2]; \
    _Pragma("unroll") for(int i=0;i<4;i++) av[i] = *(const bf16x8*)(sA[CUR]+offA[i]); \
    _Pragma("unroll") for(int j=0;j<2;j++) wv[j] = *(const bf16x8*)(sW[CUR]+offW[j]); \
    _Pragma("unroll") for(int j=0;j<2;j++){ \
      _Pragma("unroll") for(int i=0;i<4;i++) acc[i][j] = mfma16(av[i], wv[j], acc[i][j]); } \
    __syncthreads(); }

  G_STAGE(0,0); __syncthreads();
  for(int t=0;t<nk;t+=2){ G_STEP(0,t); G_STEP(1,t+1); }
#undef G_STAGE
#undef G_STEP

  #pragma unroll
  for(int i=0;i<4;i++){
    #pragma unroll
    for(int j=0;j<2;j++){
      const int col  = n0 + wn*32 + j*16 + l15;
      const float bb = bias ? bias[col] : 0.f;
      const int rowb = m0 + wm*64 + i*16 + g*4;
      #pragma unroll
      for(int jj=0;jj<4;jj++){
        float v = acc[i][j][jj] + bb;
        const int row = rowb + jj;
        if constexpr(EPI==0){ Cf[(long)row*N + col] = v; }
        else if constexpr(EPI==1){ Oh[(long)row*N + col] = f2bf(v); }
        else { Oh[(long)row*N + col] = f2bf(fmaxf(v,0.f)); }
      }
    }
  }
}

// ---------------- fused QKV projection, 8 waves, BK=32 dbuf gl16 ----------------
// W = [wq;wk;wv] concat (N=1536). Q scaled by QSC; V written permuted
// [b,h,d, t64*64 + (s&15)*4 + (s>>4)]
__global__ __launch_bounds__(512) void k_qkv(
  const u16* __restrict__ trg_hi, const u16* __restrict__ src_hi,
  const u16* __restrict__ Wh,
  const float* __restrict__ bq, const float* __restrict__ bk, const float* __restrict__ bv,
  u16* __restrict__ Qb, u16* __restrict__ Kb, u16* __restrict__ Vt)
{
  __shared__ __align__(16) u16 sA[2][128*32], sW[2][128*32];
  const int tid = threadIdx.x, w = tid>>6, l = tid&63;
  const int l15 = l&15, g = l>>4;
  const int bid = blockIdx.x;                 // grid = 1536
  const int wgid = (bid&7)*192 + (bid>>3);
  const int m0 = (wgid/12)*128, n0 = (wgid%12)*128;
  const u16* A = (n0<512)? trg_hi : src_hi;
  const float* bp = (n0<512)? bq : (n0<1024? bk : bv);
  const int nb = (n0<512)? 0 : (n0<1024? 512 : 1024);
  const int wm = w>>2, wn = w&3;
  f32x4 acc[4][2] = {};
  const int lr = l>>2, lslot = l&3;
  const int scol = 8*((lslot - ((lr>>1)&3)) & 3);
  const int wrow = w*16;
  int offA[4], offW[2];
  #pragma unroll
  for(int i=0;i<4;i++){ const int R = wm*64+i*16+l15; offA[i] = R*32 + ((g+(R>>1))&3)*8; }
  #pragma unroll
  for(int j=0;j<2;j++){ const int C = wn*32+j*16+l15; offW[j] = C*32 + ((g+(C>>1))&3)*8; }
  const u16* Ab = A  + (long)m0*512 + scol;
  const u16* Wb = Wh + (long)n0*512 + scol;

#define Q_STAGE(BUF, T) { \
    const int k0 = (T)<<5; \
    gl16(Ab + (long)(wrow+lr)*512 + k0, sA[BUF] + wrow*32); \
    gl16(Wb + (long)(wrow+lr)*512 + k0, sW[BUF] + wrow*32); }

#define Q_STEP(CUR, T) { \
    if((T)+1 < 16) Q_STAGE(CUR^1, (T)+1); \
    bf16x8 av[4], wv[2]; \
    _Pragma("unroll") for(int i=0;i<4;i++) av[i] = *(const bf16x8*)(sA[CUR]+offA[i]); \
    _Pragma("unroll") for(int j=0;j<2;j++) wv[j] = *(const bf16x8*)(sW[CUR]+offW[j]); \
    _Pragma("unroll") for(int j=0;j<2;j++){ \
      _Pragma("unroll") for(int i=0;i<4;i++) acc[i][j] = mfma16(av[i], wv[j], acc[i][j]); } \
    __syncthreads(); }

  Q_STAGE(0,0); __syncthreads();
  for(int t=0;t<16;t+=2){ Q_STEP(0,t); Q_STEP(1,t+1); }
#undef Q_STAGE
#undef Q_STEP

  #pragma unroll
  for(int i=0;i<4;i++){
    #pragma unroll
    for(int j=0;j<2;j++){
      const int col = n0 + wn*32 + j*16 + l15;
      const int cl  = col - nb;
      const float bb = bp[cl];
      const int rowb = m0 + wm*64 + i*16 + g*4;
      #pragma unroll
      for(int jj=0;jj<4;jj++){
        float v = acc[i][j][jj] + bb;
        const int row = rowb + jj;
        if(n0 < 512){ Qb[(long)row*512 + cl] = f2bf(v*QSC); }
        else if(n0 < 1024){ Kb[(long)row*512 + cl] = f2bf(v); }
        else {
          const int h = cl>>6, d = cl&63;
          const long dst = (((long)(row>>10)*8 + h)*64 + d)*1024
                         + ((row>>6)&15)*64 + (row&15)*4 + ((row>>4)&3);
          Vt[dst] = f2bf(v);
        }
      }
    }
  }
}

// ---------------- flash attention (bf16), dh=64, QBLK=128, 8 waves (R10, proven) ----------------
__global__ __launch_bounds__(512) void k_attn(
  const u16* __restrict__ Q, const u16* __restrict__ K,
  const u16* __restrict__ Vt, u16* __restrict__ O)
{
  __shared__ __align__(16) u16 sK[64*64], sV[64*64];
  __shared__ __align__(16) u16 Ph[8][16*72];
  const int bid = blockIdx.x;                 // grid = 1024
  const int wg = (bid&7)*128 + (bid>>3);      // XCD-chunked
  const int q0 = (wg&7)*128, hd = (wg>>3)&7, b = wg>>6;
  const int tid = threadIdx.x, w = tid>>6, l = tid&63, l15 = l&15, g = l>>4;
  const int qrow = q0 + w*16 + l15;
  const long qoff = (long)(b*1024 + qrow)*512 + hd*64 + g*8;
  bf16x8 qf[2] = { ld8(Q+qoff), ld8(Q+qoff+32) };
  const int srw = l>>3, sslot = l&7;
  const int scol = 8*(sslot ^ srw);
  const int rows = w*8;                                // wave-uniform LDS base row
  const u16* Kb = K + (long)b*1024*512 + hd*64;        // [s][512]
  const u16* Vb = Vt + (long)(b*8+hd)*64*1024;         // [d][1024] (k'-permuted)
  f32x4 rs = {};
  f32x4 ctx[4] = {};
  for(int s0=0;s0<1024;s0+=64){
    gl16(Kb + (long)(s0+rows+srw)*512 + scol, sK + rows*64);
    gl16(Vb + (long)(rows+srw)*1024 + s0 + scol, sV + rows*64);
    __syncthreads();
    f32x4 sv[4];
    #pragma unroll
    for(int sf=0;sf<4;sf++){
      const int row = sf*16 + l15;
      f32x4 a = {};
      #pragma unroll
      for(int h=0;h<2;h++){
        const int ch = (g + 4*h) ^ (row&7);
        a = mfma16(qf[h], *(const bf16x8*)(sK + row*64 + ch*8), a);
      }
      sv[sf] = a;
    }
    float p[4][4];
    #pragma unroll
    for(int sf=0;sf<4;sf++){
      #pragma unroll
      for(int j=0;j<4;j++){
        p[sf][j] = exp2f(sv[sf][j]);
        rs[j] += p[sf][j];
      }
    }
    #pragma unroll
    for(int j=0;j<4;j++){
      uint2 pk = { cvtpk(p[0][j], p[1][j]), cvtpk(p[2][j], p[3][j]) };
      *(uint2*)(&Ph[w][(g*4+j)*72 + l15*4]) = pk;   // k' = l15*4 + sf
    }
    #pragma unroll
    for(int ss=0;ss<2;ss++){
      bf16x8 pa = *(const bf16x8*)(&Ph[w][l15*72 + ss*32 + g*8]);
      #pragma unroll
      for(int df=0;df<4;df++){
        const int row = df*16 + l15;
        const int ch = (ss*4 + g) ^ (row&7);
        ctx[df] = mfma16(pa, *(const bf16x8*)(sV + row*64 + ch*8), ctx[df]);
      }
    }
    __syncthreads();
  }
  float inv[4];
  #pragma unroll
  for(int j=0;j<4;j++){
    float t = rs[j];
    #pragma unroll
    for(int mask=1;mask<16;mask<<=1) t += __shfl_xor(t, mask);
    inv[j] = 1.f/t;
  }
  #pragma unroll
  for(int df=0;df<4;df++){
    #pragma unroll
    for(int j=0;j<4;j++){
      const float v = ctx[df][j] * inv[j];
      const long off = (long)(b*1024 + q0 + w*16 + g*4 + j)*512 + hd*64 + df*16 + l15;
      O[off] = f2bf(v);
    }
  }
}

// ---------------- fused residual + LayerNorm, bf16 i/o (one wave per row) ----------------
// XAF: 1 = xa is fp32 (trg input), 0 = xa is bf16. xb always bf16. Output bf16 (+norms).
template<int XAF>
__global__ __launch_bounds__(256) void k_ln(
  const float* __restrict__ xaf, const u16* __restrict__ xab,
  const u16* __restrict__ xbb,
  const float* __restrict__ gg, const float* __restrict__ bvec,
  u16* __restrict__ yh, float* __restrict__ norms)
{
  const int w = threadIdx.x>>6, l = threadIdx.x&63;
  const long rrow = (long)blockIdx.x*4 + w;
  const long base = rrow*512 + l*8;
  float va[8];
  if constexpr(XAF){
    float4 a0 = *(const float4*)(xaf+base), a1 = *(const float4*)(xaf+base+4);
    va[0]=a0.x; va[1]=a0.y; va[2]=a0.z; va[3]=a0.w;
    va[4]=a1.x; va[5]=a1.y; va[6]=a1.z; va[7]=a1.w;
  } else {
    ushort4 a0 = *(const ushort4*)(xab+base), a1 = *(const ushort4*)(xab+base+4);
    va[0]=bf2f(a0.x); va[1]=bf2f(a0.y); va[2]=bf2f(a0.z); va[3]=bf2f(a0.w);
    va[4]=bf2f(a1.x); va[5]=bf2f(a1.y); va[6]=bf2f(a1.z); va[7]=bf2f(a1.w);
  }
  ushort4 b0 = *(const ushort4*)(xbb+base), b1 = *(const ushort4*)(xbb+base+4);
  float v[8] = {va[0]+bf2f(b0.x), va[1]+bf2f(b0.y), va[2]+bf2f(b0.z), va[3]+bf2f(b0.w),
                va[4]+bf2f(b1.x), va[5]+bf2f(b1.y), va[6]+bf2f(b1.z), va[7]+bf2f(b1.w)};
  float s=0.f, q=0.f;
  #pragma unroll
  for(int j=0;j<8;j++){ s += v[j]; q += v[j]*v[j]; }
  #pragma unroll
  for(int mask=1;mask<64;mask<<=1){ s += __shfl_xor(s,mask); q += __shfl_xor(q,mask); }
  const float mu  = s*(1.f/512.f);
  const float var = q*(1.f/512.f) - mu*mu;
  const float rstd = rsqrtf(var + 1e-5f);
  float y[8]; float nq = 0.f;
  #pragma unroll
  for(int j=0;j<8;j++){
    const int c = l*8+j;
    y[j] = (v[j]-mu)*rstd*gg[c] + bvec[c];
    nq += y[j]*y[j];
  }
  u16 hv[8];
  #pragma unroll
  for(int j=0;j<8;j++){ hv[j]=f2bf(y[j]); }
  ushort4 hh0={hv[0],hv[1],hv[2],hv[3]}, hh1={hv[4],hv[5],hv[6],hv[7]};
  *(ushort4*)(yh+base)=hh0; *(ushort4*)(yh+base+4)=hh1;
  if(norms){
    #pragma unroll
    for(int mask=1;mask<64;mask<<=1) nq += __shfl_xor(nq,mask);
    if(l==0) norms[rrow] = sqrtf(nq);
  }
}

// ---------------- norm-softmax pooling, stage 1 (bf16 x2) ----------------
__global__ __launch_bounds__(256) void k_pool2(const u16* __restrict__ x2,
   const float* __restrict__ norms, float* __restrict__ partial)
{
  const int b = blockIdx.y, tc = blockIdx.z;
  const int col = blockIdx.x*256 + threadIdx.x;
  __shared__ float wsm[1024];
  __shared__ float red[4];
  const int tid = threadIdx.x, w = tid>>6, l = tid&63;
  float lm = -1e30f;
  for(int i=tid;i<1024;i+=256){ const float n = norms[b*1024+i]; wsm[i]=n; lm=fmaxf(lm,n); }
  #pragma unroll
  for(int mask=1;mask<64;mask<<=1) lm = fmaxf(lm, __shfl_xor(lm,mask));
  __syncthreads();
  if(l==0) red[w]=lm;
  __syncthreads();
  const float bm = fmaxf(fmaxf(red[0],red[1]), fmaxf(red[2],red[3]));
  __syncthreads();
  float ls = 0.f;
  for(int i=tid;i<1024;i+=256){ const float e = __expf(wsm[i]-bm); wsm[i]=e; ls+=e; }
  #pragma unroll
  for(int mask=1;mask<64;mask<<=1) ls += __shfl_xor(ls,mask);
  __syncthreads();
  if(l==0) red[w]=ls;
  __syncthreads();
  const float inv = 1.f/(red[0]+red[1]+red[2]+red[3]);
  float acc = 0.f;
  const int t0 = tc*128;
  for(int t=t0;t<t0+128;t++) acc += wsm[t]*bf2f(x2[((long)b*1024+t)*512 + col]);
  partial[((long)tc*16 + b)*512 + col] = acc*inv;
}

// ---------------- pooling, stage 2: fold 8 partials ----------------
__global__ __launch_bounds__(256) void k_poolr(const float* __restrict__ partial,
   float* __restrict__ pooled)
{
  const int i = blockIdx.x*256 + threadIdx.x;   // 8192 outputs
  float a = 0.f;
  #pragma unroll
  for(int tc=0;tc<8;tc++) a += partial[tc*8192 + i];
  pooled[i] = a;
}

// ---------------- classifier head (tiny) ----------------
__global__ __launch_bounds__(256) void k_head(const float* __restrict__ pooled,
  const float* __restrict__ w1, const float* __restrict__ b1,
  const float* __restrict__ w2, const float* __restrict__ b2,
  float* __restrict__ out)
{
  __shared__ float ps[16*512];
  __shared__ float h1[16*256];
  const int tid = threadIdx.x;
  for(int i=tid;i<16*512;i+=256) ps[i]=pooled[i];
  __syncthreads();
  float acc[16] = {};
  for(int k=0;k<512;k++){
    const float wv = w1[tid*512+k];
    #pragma unroll
    for(int i=0;i<16;i++) acc[i] += ps[i*512+k]*wv;
  }
  #pragma unroll
  for(int i=0;i<16;i++) h1[i*256+tid] = fmaxf(acc[i]+b1[tid], 0.f);
  __syncthreads();
  if(tid<32){
    const int i = tid>>1, o = tid&1;
    float a = b2[o];
    for(int k=0;k<256;k++) a += h1[i*256+k]*w2[o*256+k];
    out[i*2+o] = a;
  }
}

extern "C" void kernel_launch(void* const* d_in, const int* in_sizes, int n_in,
                              void* d_out, int out_size, void* d_ws, size_t ws_size,
                              hipStream_t stream)
{
  const float* trg  = (const float*)d_in[0];
  const float* src  = (const float*)d_in[1];
  const float* ln_g = (const float*)d_in[2];
  const float* ln_b = (const float*)d_in[3];
  const float* wq   = (const float*)d_in[4];  const float* bq  = (const float*)d_in[5];
  const float* wk   = (const float*)d_in[6];  const float* bk  = (const float*)d_in[7];
  const float* wv   = (const float*)d_in[8];  const float* bv  = (const float*)d_in[9];
  const float* wo   = (const float*)d_in[10]; const float* bo  = (const float*)d_in[11];
  const float* pf1w = (const float*)d_in[12]; const float* pf1b= (const float*)d_in[13];
  const float* pf2w = (const float*)d_in[14]; const float* pf2b= (const float*)d_in[15];
  const float* fc1w = (const float*)d_in[16]; const float* fc1b= (const float*)d_in[17];
  const float* fc2w = (const float*)d_in[18]; const float* fc2b= (const float*)d_in[19];
  float* out = (float*)d_out;

  // ---- workspace: 7 bf16 planes (112 MiB) + ~9 MiB weights/misc ----
  // liveness: split2{W:4,5} qkv{R:4,5 W:0,1,2} attn{R:0,1,2 W:3} wo{R:3 W:4}
  //           LN1{R:trg,4 W:5} ff1{R:5 W:0-3} ff2{R:0-3 W:4} LN2{R:5,4 W:6} pool{R:6}
  char* ws = (char*)d_ws;
  const size_t PL = (size_t)16384*512*2;          // one bf16 plane (16 MiB)
  auto P = [&](int i)->u16*{ return (u16*)(ws + (size_t)i*PL); };
  u16 *Qb=P(0), *Kb=P(1), *Vt=P(2), *ctx=P(3);
  u16 *trg_hi=P(4), *src_hi=P(5);                 // dead after qkv
  u16 *sa_bf = P(4);                              // wo out (over trg_hi), LN1 in
  u16 *x1_hi = P(5);                              // LN1 out (over src_hi); ff1 + LN2-residual in
  u16 *h_hi  = P(0);                              // planes 0-3 (64 MiB, over Q/K/V/ctx)
  u16 *ffb_bf= P(4);                              // ff2 out (over sa, dead after LN1)
  u16 *x2_bf = P(6);                              // LN2 out
  size_t off = 7*PL;
  auto carve = [&](size_t n)->char*{ char* p = ws+off; off += n; return p; };
  u16* wqkv_hi=(u16*)carve((size_t)1536*512*2);
  u16* wo_hi=(u16*)carve(512*512*2);
  u16* p1_hi=(u16*)carve((size_t)2048*512*2);
  u16* p2_hi=(u16*)carve((size_t)512*2048*2);
  float* norms  = (float*)carve(16384*4);
  float* partial= (float*)carve(8*16*512*4);
  float* pooled = (float*)carve(16*512*4);
  (void)ws_size; (void)in_sizes; (void)n_in; (void)out_size;

  const int NTOK = 16384;

  // input + weight splits (2 launches)
  k_split2<<<dim3(8192,2),256,0,stream>>>(trg, src, trg_hi, src_hi, NTOK*512);
  SplitW sw;
  sw.s[0]=wq;  sw.d[0]=wqkv_hi;           sw.n[0]=512*512;
  sw.s[1]=wk;  sw.d[1]=wqkv_hi+512*512;   sw.n[1]=512*512;
  sw.s[2]=wv;  sw.d[2]=wqkv_hi+1024*512;  sw.n[2]=512*512;
  sw.s[3]=wo;  sw.d[3]=wo_hi;             sw.n[3]=512*512;
  sw.s[4]=pf1w; sw.d[4]=p1_hi;            sw.n[4]=2048*512;
  sw.s[5]=pf2w; sw.d[5]=p2_hi;            sw.n[5]=512*2048;
  k_splitw<<<dim3(512,6),256,0,stream>>>(sw);

  // fused QKV projection (8-wave gl16 dbuf)
  k_qkv<<<dim3(1536),512,0,stream>>>(trg_hi,src_hi,wqkv_hi,bq,bk,bv,Qb,Kb,Vt);

  // attention (QBLK=128, 8 waves, shared single-buffer K/V)
  k_attn<<<dim3(1024),512,0,stream>>>(Qb,Kb,Vt,ctx);

  // output projection (bf16 out) + LN1 (bf16 out only)
  k_gemm<1><<<dim3(4,128),512,0,stream>>>(ctx,wo_hi,bo,NTOK,512,512,nullptr,sa_bf);
  k_ln<1><<<dim3(4096),256,0,stream>>>(trg, nullptr, sa_bf, ln_g, ln_b, x1_hi, nullptr);

  // FFN + LN2 (+ row norms); all bf16 intermediates
  k_gemm<2><<<dim3(16,128),512,0,stream>>>(x1_hi,p1_hi,pf1b,NTOK,2048,512,nullptr,h_hi);
  k_gemm<1><<<dim3(4,128),512,0,stream>>>(h_hi,p2_hi,pf2b,NTOK,512,2048,nullptr,ffb_bf);
  k_ln<0><<<dim3(4096),256,0,stream>>>(nullptr, x1_hi, ffb_bf, ln_g, ln_b, x2_bf, norms);

  // pooling (parallel 2-stage) + head
  k_pool2<<<dim3(2,16,8),256,0,stream>>>(x2_bf, norms, partial);
  k_poolr<<<dim3(32),256,0,stream>>>(partial, pooled);
  k_head<<<1,256,0,stream>>>(pooled, fc1w, fc1b, fc2w, fc2b, out);
}

// Round 17
// 308.623 us; speedup vs baseline: 1.0601x; 1.0312x over previous
//
#include <hip/hip_runtime.h>

typedef __bf16 bf16x8 __attribute__((ext_vector_type(8)));
typedef float f32x4 __attribute__((ext_vector_type(4)));
typedef unsigned short u16;

__device__ __forceinline__ u16 f2bf(float f){
  unsigned u = __builtin_bit_cast(unsigned, f);
  u += 0x7fffu + ((u>>16)&1u);
  return (u16)(u>>16);
}
__device__ __forceinline__ float bf2f(u16 h){
  unsigned u = ((unsigned)h)<<16; return __builtin_bit_cast(float,u);
}
__device__ __forceinline__ bf16x8 ld8(const u16* p){ return *(const bf16x8*)p; }
__device__ __forceinline__ f32x4 mfma16(bf16x8 a, bf16x8 b, f32x4 c){
  return __builtin_amdgcn_mfma_f32_16x16x32_bf16(a,b,c,0,0,0);
}
__device__ __forceinline__ void gl16(const u16* g, u16* l){
  __builtin_amdgcn_global_load_lds(
    (const __attribute__((address_space(1))) unsigned int*)g,
    (__attribute__((address_space(3))) unsigned int*)l, 16, 0, 0);
}
// pack 2 f32 -> 2 bf16 (RNE), lo=a hi=b
__device__ __forceinline__ unsigned cvtpk(float a, float b){
  unsigned r;
  asm("v_cvt_pk_bf16_f32 %0, %1, %2" : "=v"(r) : "v"(a), "v"(b));
  return r;
}

#define QSC 0.18033688f   /* 0.125 * log2(e), folded into stored Q */

// ---------------- fused input split: trg+src fp32 -> bf16 ----------------
__global__ __launch_bounds__(256) void k_split2(const float* __restrict__ a,
    const float* __restrict__ b, u16* __restrict__ da, u16* __restrict__ db, int n){
  const float* s = blockIdx.y ? b : a;
  u16* d = blockIdx.y ? db : da;
  int i = (blockIdx.x*256 + threadIdx.x)*4;
  const int stride = gridDim.x*256*4;
  for(; i<n; i+=stride){
    float4 v = *(const float4*)(s+i);
    ushort4 H = {f2bf(v.x),f2bf(v.y),f2bf(v.z),f2bf(v.w)};
    *(ushort4*)(d+i)=H;
  }
}

// ---------------- fused weight splits (6 tensors in one launch) ----------------
struct SplitW { const float* s[6]; u16* d[6]; int n[6]; };
__global__ __launch_bounds__(256) void k_splitw(SplitW P){
  const int y = blockIdx.y;
  const float* s = P.s[y]; u16* d = P.d[y]; const int n = P.n[y];
  int i = (blockIdx.x*256 + threadIdx.x)*4;
  const int stride = gridDim.x*256*4;
  for(; i<n; i+=stride){
    float4 v = *(const float4*)(s+i);
    ushort4 H = {f2bf(v.x),f2bf(v.y),f2bf(v.z),f2bf(v.w)};
    *(ushort4*)(d+i)=H;
  }
}

// ---------------- 1-term bf16 GEMM, BK=64, dbuf, 8 waves (64x32/wave) ----------------
// C[m,n] = sum_k A[m,k]*W[n,k] + bias.  EPI: 0 = fp32 out, 1 = bf16 out, 2 = relu+bf16 out
// LDS rotation swizzle (8 slots/row): slot p of row R holds chunk (p-(R>>1))&7.
template<int EPI>
__global__ __launch_bounds__(512) void k_gemm(
  const u16* __restrict__ A, const u16* __restrict__ W,
  const float* __restrict__ bias, int M, int N, int K,
  float* __restrict__ Cf, u16* __restrict__ Oh)
{
  __shared__ __align__(16) u16 sA[2][128*64], sW[2][128*64];
  const int tid = threadIdx.x, w = tid>>6, l = tid&63;
  const int l15 = l&15, g = l>>4;
  const int gx = gridDim.x;
  const int bid = blockIdx.y*gx + blockIdx.x;
  const int nwg = gx*gridDim.y;
  const int wgid = (bid&7)*(nwg>>3) + (bid>>3);
  const int m0 = (wgid/gx)*128, n0 = (wgid%gx)*128;
  const int wm = w>>2, wn = w&3;            // 2x4 wave grid, 64x32 out each
  f32x4 acc[4][2] = {};
  const int wrow = w*16;
  const int sr = l>>3, sslot = l&7;         // staging: 8 rows per gl16
  int scolA[2];
  #pragma unroll
  for(int i=0;i<2;i++){
    const int R = wrow + i*8 + sr;
    scolA[i] = 8*((sslot - ((R>>1)&7)) & 7);
  }
  int offA[4][2], offW[2][2];
  #pragma unroll
  for(int i=0;i<4;i++){
    const int R = wm*64+i*16+l15;
    #pragma unroll
    for(int kk=0;kk<2;kk++) offA[i][kk] = R*64 + (((g+4*kk)+((R>>1)&7))&7)*8;
  }
  #pragma unroll
  for(int j=0;j<2;j++){
    const int C = wn*32+j*16+l15;
    #pragma unroll
    for(int kk=0;kk<2;kk++) offW[j][kk] = C*64 + (((g+4*kk)+((C>>1)&7))&7)*8;
  }
  const u16* Ab = A + (long)m0*K;
  const u16* Wb = W + (long)n0*K;
  const int nk = K>>6;

#define G_STAGE(BUF, T) { \
    const int k0 = (T)<<6; \
    _Pragma("unroll") \
    for(int i=0;i<2;i++){ \
      const int rows = wrow + i*8; \
      gl16(Ab + (long)(rows+sr)*K + k0 + scolA[i], sA[BUF] + rows*64); \
      gl16(Wb + (long)(rows+sr)*K + k0 + scolA[i], sW[BUF] + rows*64); \
    } }

#define G_STEP(CUR, T) { \
    if((T)+1 < nk) G_STAGE(CUR^1, (T)+1); \
    _Pragma("unroll") \
    for(int kk=0;kk<2;kk++){ \
      bf16x8 av[4], wv[2]; \
      _Pragma("unroll") for(int i=0;i<4;i++) av[i] = *(const bf16x8*)(sA[CUR]+offA[i][kk]); \
      _Pragma("unroll") for(int j=0;j<2;j++) wv[j] = *(const bf16x8*)(sW[CUR]+offW[j][kk]); \
      _Pragma("unroll") for(int j=0;j<2;j++){ \
        _Pragma("unroll") for(int i=0;i<4;i++) acc[i][j] = mfma16(av[i], wv[j], acc[i][j]); } \
    } \
    __syncthreads(); }

  G_STAGE(0,0); __syncthreads();
  for(int t=0;t<nk;t+=2){ G_STEP(0,t); G_STEP(1,t+1); }
#undef G_STAGE
#undef G_STEP

  #pragma unroll
  for(int i=0;i<4;i++){
    #pragma unroll
    for(int j=0;j<2;j++){
      const int col  = n0 + wn*32 + j*16 + l15;
      const float bb = bias ? bias[col] : 0.f;
      const int rowb = m0 + wm*64 + i*16 + g*4;
      #pragma unroll
      for(int jj=0;jj<4;jj++){
        float v = acc[i][j][jj] + bb;
        const int row = rowb + jj;
        if constexpr(EPI==0){ Cf[(long)row*N + col] = v; }
        else if constexpr(EPI==1){ Oh[(long)row*N + col] = f2bf(v); }
        else { Oh[(long)row*N + col] = f2bf(fmaxf(v,0.f)); }
      }
    }
  }
}

// ---------------- fused QKV projection, 8 waves, BK=64 dbuf gl16 ----------------
// W = [wq;wk;wv] concat (N=1536). Q scaled by QSC; V written permuted
// [b,h,d, t64*64 + (s&15)*4 + (s>>4)]
__global__ __launch_bounds__(512) void k_qkv(
  const u16* __restrict__ trg_hi, const u16* __restrict__ src_hi,
  const u16* __restrict__ Wh,
  const float* __restrict__ bq, const float* __restrict__ bk, const float* __restrict__ bv,
  u16* __restrict__ Qb, u16* __restrict__ Kb, u16* __restrict__ Vt)
{
  __shared__ __align__(16) u16 sA[2][128*64], sW[2][128*64];
  const int tid = threadIdx.x, w = tid>>6, l = tid&63;
  const int l15 = l&15, g = l>>4;
  const int bid = blockIdx.x;                 // grid = 1536
  const int wgid = (bid&7)*192 + (bid>>3);
  const int m0 = (wgid/12)*128, n0 = (wgid%12)*128;
  const u16* A = (n0<512)? trg_hi : src_hi;
  const float* bp = (n0<512)? bq : (n0<1024? bk : bv);
  const int nb = (n0<512)? 0 : (n0<1024? 512 : 1024);
  const int wm = w>>2, wn = w&3;
  f32x4 acc[4][2] = {};
  const int wrow = w*16;
  const int sr = l>>3, sslot = l&7;
  int scolA[2];
  #pragma unroll
  for(int i=0;i<2;i++){
    const int R = wrow + i*8 + sr;
    scolA[i] = 8*((sslot - ((R>>1)&7)) & 7);
  }
  int offA[4][2], offW[2][2];
  #pragma unroll
  for(int i=0;i<4;i++){
    const int R = wm*64+i*16+l15;
    #pragma unroll
    for(int kk=0;kk<2;kk++) offA[i][kk] = R*64 + (((g+4*kk)+((R>>1)&7))&7)*8;
  }
  #pragma unroll
  for(int j=0;j<2;j++){
    const int C = wn*32+j*16+l15;
    #pragma unroll
    for(int kk=0;kk<2;kk++) offW[j][kk] = C*64 + (((g+4*kk)+((C>>1)&7))&7)*8;
  }
  const u16* Ab = A  + (long)m0*512;
  const u16* Wb = Wh + (long)n0*512;

#define Q_STAGE(BUF, T) { \
    const int k0 = (T)<<6; \
    _Pragma("unroll") \
    for(int i=0;i<2;i++){ \
      const int rows = wrow + i*8; \
      gl16(Ab + (long)(rows+sr)*512 + k0 + scolA[i], sA[BUF] + rows*64); \
      gl16(Wb + (long)(rows+sr)*512 + k0 + scolA[i], sW[BUF] + rows*64); \
    } }

#define Q_STEP(CUR, T) { \
    if((T)+1 < 8) Q_STAGE(CUR^1, (T)+1); \
    _Pragma("unroll") \
    for(int kk=0;kk<2;kk++){ \
      bf16x8 av[4], wv[2]; \
      _Pragma("unroll") for(int i=0;i<4;i++) av[i] = *(const bf16x8*)(sA[CUR]+offA[i][kk]); \
      _Pragma("unroll") for(int j=0;j<2;j++) wv[j] = *(const bf16x8*)(sW[CUR]+offW[j][kk]); \
      _Pragma("unroll") for(int j=0;j<2;j++){ \
        _Pragma("unroll") for(int i=0;i<4;i++) acc[i][j] = mfma16(av[i], wv[j], acc[i][j]); } \
    } \
    __syncthreads(); }

  Q_STAGE(0,0); __syncthreads();
  for(int t=0;t<8;t+=2){ Q_STEP(0,t); Q_STEP(1,t+1); }
#undef Q_STAGE
#undef Q_STEP

  #pragma unroll
  for(int i=0;i<4;i++){
    #pragma unroll
    for(int j=0;j<2;j++){
      const int col = n0 + wn*32 + j*16 + l15;
      const int cl  = col - nb;
      const float bb = bp[cl];
      const int rowb = m0 + wm*64 + i*16 + g*4;
      #pragma unroll
      for(int jj=0;jj<4;jj++){
        float v = acc[i][j][jj] + bb;
        const int row = rowb + jj;
        if(n0 < 512){ Qb[(long)row*512 + cl] = f2bf(v*QSC); }
        else if(n0 < 1024){ Kb[(long)row*512 + cl] = f2bf(v); }
        else {
          const int h = cl>>6, d = cl&63;
          const long dst = (((long)(row>>10)*8 + h)*64 + d)*1024
                         + ((row>>6)&15)*64 + (row&15)*4 + ((row>>4)&3);
          Vt[dst] = f2bf(v);
        }
      }
    }
  }
}

// ---------------- flash attention (bf16), dh=64, QBLK=128, 8 waves (R10, proven) ----------------
__global__ __launch_bounds__(512) void k_attn(
  const u16* __restrict__ Q, const u16* __restrict__ K,
  const u16* __restrict__ Vt, u16* __restrict__ O)
{
  __shared__ __align__(16) u16 sK[64*64], sV[64*64];
  __shared__ __align__(16) u16 Ph[8][16*72];
  const int bid = blockIdx.x;                 // grid = 1024
  const int wg = (bid&7)*128 + (bid>>3);      // XCD-chunked
  const int q0 = (wg&7)*128, hd = (wg>>3)&7, b = wg>>6;
  const int tid = threadIdx.x, w = tid>>6, l = tid&63, l15 = l&15, g = l>>4;
  const int qrow = q0 + w*16 + l15;
  const long qoff = (long)(b*1024 + qrow)*512 + hd*64 + g*8;
  bf16x8 qf[2] = { ld8(Q+qoff), ld8(Q+qoff+32) };
  const int srw = l>>3, sslot = l&7;
  const int scol = 8*(sslot ^ srw);
  const int rows = w*8;                                // wave-uniform LDS base row
  const u16* Kb = K + (long)b*1024*512 + hd*64;        // [s][512]
  const u16* Vb = Vt + (long)(b*8+hd)*64*1024;         // [d][1024] (k'-permuted)
  f32x4 rs = {};
  f32x4 ctx[4] = {};
  for(int s0=0;s0<1024;s0+=64){
    gl16(Kb + (long)(s0+rows+srw)*512 + scol, sK + rows*64);
    gl16(Vb + (long)(rows+srw)*1024 + s0 + scol, sV + rows*64);
    __syncthreads();
    f32x4 sv[4];
    #pragma unroll
    for(int sf=0;sf<4;sf++){
      const int row = sf*16 + l15;
      f32x4 a = {};
      #pragma unroll
      for(int h=0;h<2;h++){
        const int ch = (g + 4*h) ^ (row&7);
        a = mfma16(qf[h], *(const bf16x8*)(sK + row*64 + ch*8), a);
      }
      sv[sf] = a;
    }
    float p[4][4];
    #pragma unroll
    for(int sf=0;sf<4;sf++){
      #pragma unroll
      for(int j=0;j<4;j++){
        p[sf][j] = exp2f(sv[sf][j]);
        rs[j] += p[sf][j];
      }
    }
    #pragma unroll
    for(int j=0;j<4;j++){
      uint2 pk = { cvtpk(p[0][j], p[1][j]), cvtpk(p[2][j], p[3][j]) };
      *(uint2*)(&Ph[w][(g*4+j)*72 + l15*4]) = pk;   // k' = l15*4 + sf
    }
    #pragma unroll
    for(int ss=0;ss<2;ss++){
      bf16x8 pa = *(const bf16x8*)(&Ph[w][l15*72 + ss*32 + g*8]);
      #pragma unroll
      for(int df=0;df<4;df++){
        const int row = df*16 + l15;
        const int ch = (ss*4 + g) ^ (row&7);
        ctx[df] = mfma16(pa, *(const bf16x8*)(sV + row*64 + ch*8), ctx[df]);
      }
    }
    __syncthreads();
  }
  float inv[4];
  #pragma unroll
  for(int j=0;j<4;j++){
    float t = rs[j];
    #pragma unroll
    for(int mask=1;mask<16;mask<<=1) t += __shfl_xor(t, mask);
    inv[j] = 1.f/t;
  }
  #pragma unroll
  for(int df=0;df<4;df++){
    #pragma unroll
    for(int j=0;j<4;j++){
      const float v = ctx[df][j] * inv[j];
      const long off = (long)(b*1024 + q0 + w*16 + g*4 + j)*512 + hd*64 + df*16 + l15;
      O[off] = f2bf(v);
    }
  }
}

// ---------------- fused residual + LayerNorm, bf16 i/o (one wave per row) ----------------
// XAF: 1 = xa is fp32 (trg input), 0 = xa is bf16. xb always bf16. Output bf16 (+norms).
template<int XAF>
__global__ __launch_bounds__(256) void k_ln(
  const float* __restrict__ xaf, const u16* __restrict__ xab,
  const u16* __restrict__ xbb,
  const float* __restrict__ gg, const float* __restrict__ bvec,
  u16* __restrict__ yh, float* __restrict__ norms)
{
  const int w = threadIdx.x>>6, l = threadIdx.x&63;
  const long rrow = (long)blockIdx.x*4 + w;
  const long base = rrow*512 + l*8;
  float va[8];
  if constexpr(XAF){
    float4 a0 = *(const float4*)(xaf+base), a1 = *(const float4*)(xaf+base+4);
    va[0]=a0.x; va[1]=a0.y; va[2]=a0.z; va[3]=a0.w;
    va[4]=a1.x; va[5]=a1.y; va[6]=a1.z; va[7]=a1.w;
  } else {
    ushort4 a0 = *(const ushort4*)(xab+base), a1 = *(const ushort4*)(xab+base+4);
    va[0]=bf2f(a0.x); va[1]=bf2f(a0.y); va[2]=bf2f(a0.z); va[3]=bf2f(a0.w);
    va[4]=bf2f(a1.x); va[5]=bf2f(a1.y); va[6]=bf2f(a1.z); va[7]=bf2f(a1.w);
  }
  ushort4 b0 = *(const ushort4*)(xbb+base), b1 = *(const ushort4*)(xbb+base+4);
  float v[8] = {va[0]+bf2f(b0.x), va[1]+bf2f(b0.y), va[2]+bf2f(b0.z), va[3]+bf2f(b0.w),
                va[4]+bf2f(b1.x), va[5]+bf2f(b1.y), va[6]+bf2f(b1.z), va[7]+bf2f(b1.w)};
  float s=0.f, q=0.f;
  #pragma unroll
  for(int j=0;j<8;j++){ s += v[j]; q += v[j]*v[j]; }
  #pragma unroll
  for(int mask=1;mask<64;mask<<=1){ s += __shfl_xor(s,mask); q += __shfl_xor(q,mask); }
  const float mu  = s*(1.f/512.f);
  const float var = q*(1.f/512.f) - mu*mu;
  const float rstd = rsqrtf(var + 1e-5f);
  float y[8]; float nq = 0.f;
  #pragma unroll
  for(int j=0;j<8;j++){
    const int c = l*8+j;
    y[j] = (v[j]-mu)*rstd*gg[c] + bvec[c];
    nq += y[j]*y[j];
  }
  u16 hv[8];
  #pragma unroll
  for(int j=0;j<8;j++){ hv[j]=f2bf(y[j]); }
  ushort4 hh0={hv[0],hv[1],hv[2],hv[3]}, hh1={hv[4],hv[5],hv[6],hv[7]};
  *(ushort4*)(yh+base)=hh0; *(ushort4*)(yh+base+4)=hh1;
  if(norms){
    #pragma unroll
    for(int mask=1;mask<64;mask<<=1) nq += __shfl_xor(nq,mask);
    if(l==0) norms[rrow] = sqrtf(nq);
  }
}

// ---------------- norm-softmax pooling, stage 1 (bf16 x2) ----------------
__global__ __launch_bounds__(256) void k_pool2(const u16* __restrict__ x2,
   const float* __restrict__ norms, float* __restrict__ partial)
{
  const int b = blockIdx.y, tc = blockIdx.z;
  const int col = blockIdx.x*256 + threadIdx.x;
  __shared__ float wsm[1024];
  __shared__ float red[4];
  const int tid = threadIdx.x, w = tid>>6, l = tid&63;
  float lm = -1e30f;
  for(int i=tid;i<1024;i+=256){ const float n = norms[b*1024+i]; wsm[i]=n; lm=fmaxf(lm,n); }
  #pragma unroll
  for(int mask=1;mask<64;mask<<=1) lm = fmaxf(lm, __shfl_xor(lm,mask));
  __syncthreads();
  if(l==0) red[w]=lm;
  __syncthreads();
  const float bm = fmaxf(fmaxf(red[0],red[1]), fmaxf(red[2],red[3]));
  __syncthreads();
  float ls = 0.f;
  for(int i=tid;i<1024;i+=256){ const float e = __expf(wsm[i]-bm); wsm[i]=e; ls+=e; }
  #pragma unroll
  for(int mask=1;mask<64;mask<<=1) ls += __shfl_xor(ls,mask);
  __syncthreads();
  if(l==0) red[w]=ls;
  __syncthreads();
  const float inv = 1.f/(red[0]+red[1]+red[2]+red[3]);
  float acc = 0.f;
  const int t0 = tc*128;
  for(int t=t0;t<t0+128;t++) acc += wsm[t]*bf2f(x2[((long)b*1024+t)*512 + col]);
  partial[((long)tc*16 + b)*512 + col] = acc*inv;
}

// ---------------- pooling, stage 2: fold 8 partials ----------------
__global__ __launch_bounds__(256) void k_poolr(const float* __restrict__ partial,
   float* __restrict__ pooled)
{
  const int i = blockIdx.x*256 + threadIdx.x;   // 8192 outputs
  float a = 0.f;
  #pragma unroll
  for(int tc=0;tc<8;tc++) a += partial[tc*8192 + i];
  pooled[i] = a;
}

// ---------------- classifier head (tiny) ----------------
__global__ __launch_bounds__(256) void k_head(const float* __restrict__ pooled,
  const float* __restrict__ w1, const float* __restrict__ b1,
  const float* __restrict__ w2, const float* __restrict__ b2,
  float* __restrict__ out)
{
  __shared__ float ps[16*512];
  __shared__ float h1[16*256];
  const int tid = threadIdx.x;
  for(int i=tid;i<16*512;i+=256) ps[i]=pooled[i];
  __syncthreads();
  float acc[16] = {};
  for(int k=0;k<512;k++){
    const float wv = w1[tid*512+k];
    #pragma unroll
    for(int i=0;i<16;i++) acc[i] += ps[i*512+k]*wv;
  }
  #pragma unroll
  for(int i=0;i<16;i++) h1[i*256+tid] = fmaxf(acc[i]+b1[tid], 0.f);
  __syncthreads();
  if(tid<32){
    const int i = tid>>1, o = tid&1;
    float a = b2[o];
    for(int k=0;k<256;k++) a += h1[i*256+k]*w2[o*256+k];
    out[i*2+o] = a;
  }
}

extern "C" void kernel_launch(void* const* d_in, const int* in_sizes, int n_in,
                              void* d_out, int out_size, void* d_ws, size_t ws_size,
                              hipStream_t stream)
{
  const float* trg  = (const float*)d_in[0];
  const float* src  = (const float*)d_in[1];
  const float* ln_g = (const float*)d_in[2];
  const float* ln_b = (const float*)d_in[3];
  const float* wq   = (const float*)d_in[4];  const float* bq  = (const float*)d_in[5];
  const float* wk   = (const float*)d_in[6];  const float* bk  = (const float*)d_in[7];
  const float* wv   = (const float*)d_in[8];  const float* bv  = (const float*)d_in[9];
  const float* wo   = (const float*)d_in[10]; const float* bo  = (const float*)d_in[11];
  const float* pf1w = (const float*)d_in[12]; const float* pf1b= (const float*)d_in[13];
  const float* pf2w = (const float*)d_in[14]; const float* pf2b= (const float*)d_in[15];
  const float* fc1w = (const float*)d_in[16]; const float* fc1b= (const float*)d_in[17];
  const float* fc2w = (const float*)d_in[18]; const float* fc2b= (const float*)d_in[19];
  float* out = (float*)d_out;

  // ---- workspace: 7 bf16 planes (112 MiB) + ~9 MiB weights/misc ----
  // liveness: split2{W:4,5} qkv{R:4,5 W:0,1,2} attn{R:0,1,2 W:3} wo{R:3 W:4}
  //           LN1{R:trg,4 W:5} ff1{R:5 W:0-3} ff2{R:0-3 W:4} LN2{R:5,4 W:6} pool{R:6}
  char* ws = (char*)d_ws;
  const size_t PL = (size_t)16384*512*2;          // one bf16 plane (16 MiB)
  auto P = [&](int i)->u16*{ return (u16*)(ws + (size_t)i*PL); };
  u16 *Qb=P(0), *Kb=P(1), *Vt=P(2), *ctx=P(3);
  u16 *trg_hi=P(4), *src_hi=P(5);                 // dead after qkv
  u16 *sa_bf = P(4);                              // wo out (over trg_hi), LN1 in
  u16 *x1_hi = P(5);                              // LN1 out (over src_hi); ff1 + LN2-residual in
  u16 *h_hi  = P(0);                              // planes 0-3 (64 MiB, over Q/K/V/ctx)
  u16 *ffb_bf= P(4);                              // ff2 out (over sa, dead after LN1)
  u16 *x2_bf = P(6);                              // LN2 out
  size_t off = 7*PL;
  auto carve = [&](size_t n)->char*{ char* p = ws+off; off += n; return p; };
  u16* wqkv_hi=(u16*)carve((size_t)1536*512*2);
  u16* wo_hi=(u16*)carve(512*512*2);
  u16* p1_hi=(u16*)carve((size_t)2048*512*2);
  u16* p2_hi=(u16*)carve((size_t)512*2048*2);
  float* norms  = (float*)carve(16384*4);
  float* partial= (float*)carve(8*16*512*4);
  float* pooled = (float*)carve(16*512*4);
  (void)ws_size; (void)in_sizes; (void)n_in; (void)out_size;

  const int NTOK = 16384;

  // input + weight splits (2 launches)
  k_split2<<<dim3(8192,2),256,0,stream>>>(trg, src, trg_hi, src_hi, NTOK*512);
  SplitW sw;
  sw.s[0]=wq;  sw.d[0]=wqkv_hi;           sw.n[0]=512*512;
  sw.s[1]=wk;  sw.d[1]=wqkv_hi+512*512;   sw.n[1]=512*512;
  sw.s[2]=wv;  sw.d[2]=wqkv_hi+1024*512;  sw.n[2]=512*512;
  sw.s[3]=wo;  sw.d[3]=wo_hi;             sw.n[3]=512*512;
  sw.s[4]=pf1w; sw.d[4]=p1_hi;            sw.n[4]=2048*512;
  sw.s[5]=pf2w; sw.d[5]=p2_hi;            sw.n[5]=512*2048;
  k_splitw<<<dim3(512,6),256,0,stream>>>(sw);

  // fused QKV projection (8-wave BK=64 dbuf)
  k_qkv<<<dim3(1536),512,0,stream>>>(trg_hi,src_hi,wqkv_hi,bq,bk,bv,Qb,Kb,Vt);

  // attention (QBLK=128, 8 waves, shared single-buffer K/V)
  k_attn<<<dim3(1024),512,0,stream>>>(Qb,Kb,Vt,ctx);

  // output projection (bf16 out) + LN1 (bf16 out only)
  k_gemm<1><<<dim3(4,128),512,0,stream>>>(ctx,wo_hi,bo,NTOK,512,512,nullptr,sa_bf);
  k_ln<1><<<dim3(4096),256,0,stream>>>(trg, nullptr, sa_bf, ln_g, ln_b, x1_hi, nullptr);

  // FFN + LN2 (+ row norms); all bf16 intermediates
  k_gemm<2><<<dim3(16,128),512,0,stream>>>(x1_hi,p1_hi,pf1b,NTOK,2048,512,nullptr,h_hi);
  k_gemm<1><<<dim3(4,128),512,0,stream>>>(h_hi,p2_hi,pf2b,NTOK,512,2048,nullptr,ffb_bf);
  k_ln<0><<<dim3(4096),256,0,stream>>>(nullptr, x1_hi, ffb_bf, ln_g, ln_b, x2_bf, norms);

  // pooling (parallel 2-stage) + head
  k_pool2<<<dim3(2,16,8),256,0,stream>>>(x2_bf, norms, partial);
  k_poolr<<<dim3(32),256,0,stream>>>(partial, pooled);
  k_head<<<1,256,0,stream>>>(pooled, fc1w, fc1b, fc2w, fc2b, out);
}

// Round 18
// 304.286 us; speedup vs baseline: 1.0752x; 1.0143x over previous
//
#include <hip/hip_runtime.h>

typedef __bf16 bf16x8 __attribute__((ext_vector_type(8)));
typedef float f32x4 __attribute__((ext_vector_type(4)));
typedef float f32x16 __attribute__((ext_vector_type(16)));
typedef unsigned short u16;

__device__ __forceinline__ u16 f2bf(float f){
  unsigned u = __builtin_bit_cast(unsigned, f);
  u += 0x7fffu + ((u>>16)&1u);
  return (u16)(u>>16);
}
__device__ __forceinline__ float bf2f(u16 h){
  unsigned u = ((unsigned)h)<<16; return __builtin_bit_cast(float,u);
}
__device__ __forceinline__ bf16x8 ld8(const u16* p){ return *(const bf16x8*)p; }
__device__ __forceinline__ f32x4 mfma16(bf16x8 a, bf16x8 b, f32x4 c){
  return __builtin_amdgcn_mfma_f32_16x16x32_bf16(a,b,c,0,0,0);
}
__device__ __forceinline__ f32x16 mfma32(bf16x8 a, bf16x8 b, f32x16 c){
  return __builtin_amdgcn_mfma_f32_32x32x16_bf16(a,b,c,0,0,0);
}
__device__ __forceinline__ void gl16(const u16* g, u16* l){
  __builtin_amdgcn_global_load_lds(
    (const __attribute__((address_space(1))) unsigned int*)g,
    (__attribute__((address_space(3))) unsigned int*)l, 16, 0, 0);
}
// pack 2 f32 -> 2 bf16 (RNE), lo=a hi=b
__device__ __forceinline__ unsigned cvtpk(float a, float b){
  unsigned r;
  asm("v_cvt_pk_bf16_f32 %0, %1, %2" : "=v"(r) : "v"(a), "v"(b));
  return r;
}

#define QSC 0.18033688f   /* 0.125 * log2(e), folded into stored Q */

// ---------------- fused splits: trg, src + 6 weight tensors, one launch ----------------
struct Split8 { const float* s[8]; u16* d[8]; int n[8]; };
__global__ __launch_bounds__(256) void k_split8(Split8 P){
  const int y = blockIdx.y;
  const float* s = P.s[y]; u16* d = P.d[y]; const int n = P.n[y];
  int i = (blockIdx.x*256 + threadIdx.x)*4;
  const int stride = gridDim.x*256*4;
  for(; i<n; i+=stride){
    float4 v = *(const float4*)(s+i);
    ushort4 H = {f2bf(v.x),f2bf(v.y),f2bf(v.z),f2bf(v.w)};
    *(ushort4*)(d+i)=H;
  }
}

// ---------------- 1-term bf16 GEMM, BK=64, dbuf, 8 waves, 32x32x16 MFMA ----------------
// C[m,n] = sum_k A[m,k]*W[n,k] + bias.  EPI: 0 = fp32 out, 1 = bf16 out, 2 = relu+bf16 out
// LDS rotation swizzle (8 slots/row): slot p of row R holds chunk (p-(R>>1))&7.
// Per wave: 64x32 output = 2 row-tiles of 32x32 (acc f32x16 each).
template<int EPI>
__global__ __launch_bounds__(512) void k_gemm(
  const u16* __restrict__ A, const u16* __restrict__ W,
  const float* __restrict__ bias, int M, int N, int K,
  float* __restrict__ Cf, u16* __restrict__ Oh)
{
  __shared__ __align__(16) u16 sA[2][128*64], sW[2][128*64];
  const int tid = threadIdx.x, w = tid>>6, l = tid&63;
  const int l31 = l&31, half = l>>5;
  const int gx = gridDim.x;
  const int bid = blockIdx.y*gx + blockIdx.x;
  const int nwg = gx*gridDim.y;
  const int wgid = (bid&7)*(nwg>>3) + (bid>>3);
  const int m0 = (wgid/gx)*128, n0 = (wgid%gx)*128;
  const int wm = w>>2, wn = w&3;            // 2x4 wave grid, 64x32 out each
  f32x16 acc[2] = {};
  const int wrow = w*16;
  const int sr = l>>3, sslot = l&7;         // staging: 8 rows per gl16
  int scolA[2];
  #pragma unroll
  for(int i=0;i<2;i++){
    const int R = wrow + i*8 + sr;
    scolA[i] = 8*((sslot - ((R>>1)&7)) & 7);
  }
  int offA[2][4], offW[4];
  #pragma unroll
  for(int i=0;i<2;i++){
    const int R = wm*64 + i*32 + l31;
    #pragma unroll
    for(int ks=0;ks<4;ks++) offA[i][ks] = R*64 + (((ks*2+half)+((R>>1)&7))&7)*8;
  }
  {
    const int C = wn*32 + l31;
    #pragma unroll
    for(int ks=0;ks<4;ks++) offW[ks] = C*64 + (((ks*2+half)+((C>>1)&7))&7)*8;
  }
  const u16* Ab = A + (long)m0*K;
  const u16* Wb = W + (long)n0*K;
  const int nk = K>>6;

#define G_STAGE(BUF, T) { \
    const int k0 = (T)<<6; \
    _Pragma("unroll") \
    for(int i=0;i<2;i++){ \
      const int rows = wrow + i*8; \
      gl16(Ab + (long)(rows+sr)*K + k0 + scolA[i], sA[BUF] + rows*64); \
      gl16(Wb + (long)(rows+sr)*K + k0 + scolA[i], sW[BUF] + rows*64); \
    } }

#define G_STEP(CUR, T) { \
    if((T)+1 < nk) G_STAGE(CUR^1, (T)+1); \
    _Pragma("unroll") \
    for(int ks=0;ks<4;ks++){ \
      bf16x8 bv = *(const bf16x8*)(sW[CUR]+offW[ks]); \
      acc[0] = mfma32(*(const bf16x8*)(sA[CUR]+offA[0][ks]), bv, acc[0]); \
      acc[1] = mfma32(*(const bf16x8*)(sA[CUR]+offA[1][ks]), bv, acc[1]); \
    } \
    __syncthreads(); }

  G_STAGE(0,0); __syncthreads();
  for(int t=0;t<nk;t+=2){ G_STEP(0,t); G_STEP(1,t+1); }
#undef G_STAGE
#undef G_STEP

  const int col = n0 + wn*32 + l31;
  const float bb = bias ? bias[col] : 0.f;
  #pragma unroll
  for(int i=0;i<2;i++){
    #pragma unroll
    for(int r=0;r<16;r++){
      const int row = m0 + wm*64 + i*32 + (r&3) + 8*(r>>2) + 4*half;
      float v = acc[i][r] + bb;
      if constexpr(EPI==0){ Cf[(long)row*N + col] = v; }
      else if constexpr(EPI==1){ Oh[(long)row*N + col] = f2bf(v); }
      else { Oh[(long)row*N + col] = f2bf(fmaxf(v,0.f)); }
    }
  }
}

// ---------------- fused QKV projection, 8 waves, BK=64, 32x32x16 MFMA ----------------
// W = [wq;wk;wv] concat (N=1536). Q scaled by QSC; V written permuted
// [b,h,d, t64*64 + (s&15)*4 + (s>>4)]
__global__ __launch_bounds__(512) void k_qkv(
  const u16* __restrict__ trg_hi, const u16* __restrict__ src_hi,
  const u16* __restrict__ Wh,
  const float* __restrict__ bq, const float* __restrict__ bk, const float* __restrict__ bv,
  u16* __restrict__ Qb, u16* __restrict__ Kb, u16* __restrict__ Vt)
{
  __shared__ __align__(16) u16 sA[2][128*64], sW[2][128*64];
  const int tid = threadIdx.x, w = tid>>6, l = tid&63;
  const int l31 = l&31, half = l>>5;
  const int bid = blockIdx.x;                 // grid = 1536
  const int wgid = (bid&7)*192 + (bid>>3);
  const int m0 = (wgid/12)*128, n0 = (wgid%12)*128;
  const u16* A = (n0<512)? trg_hi : src_hi;
  const float* bp = (n0<512)? bq : (n0<1024? bk : bv);
  const int nb = (n0<512)? 0 : (n0<1024? 512 : 1024);
  const int wm = w>>2, wn = w&3;
  f32x16 acc[2] = {};
  const int wrow = w*16;
  const int sr = l>>3, sslot = l&7;
  int scolA[2];
  #pragma unroll
  for(int i=0;i<2;i++){
    const int R = wrow + i*8 + sr;
    scolA[i] = 8*((sslot - ((R>>1)&7)) & 7);
  }
  int offA[2][4], offW[4];
  #pragma unroll
  for(int i=0;i<2;i++){
    const int R = wm*64 + i*32 + l31;
    #pragma unroll
    for(int ks=0;ks<4;ks++) offA[i][ks] = R*64 + (((ks*2+half)+((R>>1)&7))&7)*8;
  }
  {
    const int C = wn*32 + l31;
    #pragma unroll
    for(int ks=0;ks<4;ks++) offW[ks] = C*64 + (((ks*2+half)+((C>>1)&7))&7)*8;
  }
  const u16* Ab = A  + (long)m0*512;
  const u16* Wb = Wh + (long)n0*512;

#define Q_STAGE(BUF, T) { \
    const int k0 = (T)<<6; \
    _Pragma("unroll") \
    for(int i=0;i<2;i++){ \
      const int rows = wrow + i*8; \
      gl16(Ab + (long)(rows+sr)*512 + k0 + scolA[i], sA[BUF] + rows*64); \
      gl16(Wb + (long)(rows+sr)*512 + k0 + scolA[i], sW[BUF] + rows*64); \
    } }

#define Q_STEP(CUR, T) { \
    if((T)+1 < 8) Q_STAGE(CUR^1, (T)+1); \
    _Pragma("unroll") \
    for(int ks=0;ks<4;ks++){ \
      bf16x8 bv = *(const bf16x8*)(sW[CUR]+offW[ks]); \
      acc[0] = mfma32(*(const bf16x8*)(sA[CUR]+offA[0][ks]), bv, acc[0]); \
      acc[1] = mfma32(*(const bf16x8*)(sA[CUR]+offA[1][ks]), bv, acc[1]); \
    } \
    __syncthreads(); }

  Q_STAGE(0,0); __syncthreads();
  for(int t=0;t<8;t+=2){ Q_STEP(0,t); Q_STEP(1,t+1); }
#undef Q_STAGE
#undef Q_STEP

  const int col = n0 + wn*32 + l31;
  const int cl  = col - nb;
  const float bb = bp[cl];
  #pragma unroll
  for(int i=0;i<2;i++){
    #pragma unroll
    for(int r=0;r<16;r++){
      const int row = m0 + wm*64 + i*32 + (r&3) + 8*(r>>2) + 4*half;
      float v = acc[i][r] + bb;
      if(n0 < 512){ Qb[(long)row*512 + cl] = f2bf(v*QSC); }
      else if(n0 < 1024){ Kb[(long)row*512 + cl] = f2bf(v); }
      else {
        const int h = cl>>6, d = cl&63;
        const long dst = (((long)(row>>10)*8 + h)*64 + d)*1024
                       + ((row>>6)&15)*64 + (row&15)*4 + ((row>>4)&3);
        Vt[dst] = f2bf(v);
      }
    }
  }
}

// ---------------- flash attention (bf16), dh=64, QBLK=128, 8 waves (R10, proven) ----------------
__global__ __launch_bounds__(512) void k_attn(
  const u16* __restrict__ Q, const u16* __restrict__ K,
  const u16* __restrict__ Vt, u16* __restrict__ O)
{
  __shared__ __align__(16) u16 sK[64*64], sV[64*64];
  __shared__ __align__(16) u16 Ph[8][16*72];
  const int bid = blockIdx.x;                 // grid = 1024
  const int wg = (bid&7)*128 + (bid>>3);      // XCD-chunked
  const int q0 = (wg&7)*128, hd = (wg>>3)&7, b = wg>>6;
  const int tid = threadIdx.x, w = tid>>6, l = tid&63, l15 = l&15, g = l>>4;
  const int qrow = q0 + w*16 + l15;
  const long qoff = (long)(b*1024 + qrow)*512 + hd*64 + g*8;
  bf16x8 qf[2] = { ld8(Q+qoff), ld8(Q+qoff+32) };
  const int srw = l>>3, sslot = l&7;
  const int scol = 8*(sslot ^ srw);
  const int rows = w*8;                                // wave-uniform LDS base row
  const u16* Kb = K + (long)b*1024*512 + hd*64;        // [s][512]
  const u16* Vb = Vt + (long)(b*8+hd)*64*1024;         // [d][1024] (k'-permuted)
  f32x4 rs = {};
  f32x4 ctx[4] = {};
  for(int s0=0;s0<1024;s0+=64){
    gl16(Kb + (long)(s0+rows+srw)*512 + scol, sK + rows*64);
    gl16(Vb + (long)(rows+srw)*1024 + s0 + scol, sV + rows*64);
    __syncthreads();
    f32x4 sv[4];
    #pragma unroll
    for(int sf=0;sf<4;sf++){
      const int row = sf*16 + l15;
      f32x4 a = {};
      #pragma unroll
      for(int h=0;h<2;h++){
        const int ch = (g + 4*h) ^ (row&7);
        a = mfma16(qf[h], *(const bf16x8*)(sK + row*64 + ch*8), a);
      }
      sv[sf] = a;
    }
    float p[4][4];
    #pragma unroll
    for(int sf=0;sf<4;sf++){
      #pragma unroll
      for(int j=0;j<4;j++){
        p[sf][j] = exp2f(sv[sf][j]);
        rs[j] += p[sf][j];
      }
    }
    #pragma unroll
    for(int j=0;j<4;j++){
      uint2 pk = { cvtpk(p[0][j], p[1][j]), cvtpk(p[2][j], p[3][j]) };
      *(uint2*)(&Ph[w][(g*4+j)*72 + l15*4]) = pk;   // k' = l15*4 + sf
    }
    #pragma unroll
    for(int ss=0;ss<2;ss++){
      bf16x8 pa = *(const bf16x8*)(&Ph[w][l15*72 + ss*32 + g*8]);
      #pragma unroll
      for(int df=0;df<4;df++){
        const int row = df*16 + l15;
        const int ch = (ss*4 + g) ^ (row&7);
        ctx[df] = mfma16(pa, *(const bf16x8*)(sV + row*64 + ch*8), ctx[df]);
      }
    }
    __syncthreads();
  }
  float inv[4];
  #pragma unroll
  for(int j=0;j<4;j++){
    float t = rs[j];
    #pragma unroll
    for(int mask=1;mask<16;mask<<=1) t += __shfl_xor(t, mask);
    inv[j] = 1.f/t;
  }
  #pragma unroll
  for(int df=0;df<4;df++){
    #pragma unroll
    for(int j=0;j<4;j++){
      const float v = ctx[df][j] * inv[j];
      const long off = (long)(b*1024 + q0 + w*16 + g*4 + j)*512 + hd*64 + df*16 + l15;
      O[off] = f2bf(v);
    }
  }
}

// ---------------- fused residual + LayerNorm, bf16 i/o (one wave per row) ----------------
// XAF: 1 = xa is fp32 (trg input), 0 = xa is bf16. xb always bf16. Output bf16 (+norms).
template<int XAF>
__global__ __launch_bounds__(256) void k_ln(
  const float* __restrict__ xaf, const u16* __restrict__ xab,
  const u16* __restrict__ xbb,
  const float* __restrict__ gg, const float* __restrict__ bvec,
  u16* __restrict__ yh, float* __restrict__ norms)
{
  const int w = threadIdx.x>>6, l = threadIdx.x&63;
  const long rrow = (long)blockIdx.x*4 + w;
  const long base = rrow*512 + l*8;
  float va[8];
  if constexpr(XAF){
    float4 a0 = *(const float4*)(xaf+base), a1 = *(const float4*)(xaf+base+4);
    va[0]=a0.x; va[1]=a0.y; va[2]=a0.z; va[3]=a0.w;
    va[4]=a1.x; va[5]=a1.y; va[6]=a1.z; va[7]=a1.w;
  } else {
    ushort4 a0 = *(const ushort4*)(xab+base), a1 = *(const ushort4*)(xab+base+4);
    va[0]=bf2f(a0.x); va[1]=bf2f(a0.y); va[2]=bf2f(a0.z); va[3]=bf2f(a0.w);
    va[4]=bf2f(a1.x); va[5]=bf2f(a1.y); va[6]=bf2f(a1.z); va[7]=bf2f(a1.w);
  }
  ushort4 b0 = *(const ushort4*)(xbb+base), b1 = *(const ushort4*)(xbb+base+4);
  float v[8] = {va[0]+bf2f(b0.x), va[1]+bf2f(b0.y), va[2]+bf2f(b0.z), va[3]+bf2f(b0.w),
                va[4]+bf2f(b1.x), va[5]+bf2f(b1.y), va[6]+bf2f(b1.z), va[7]+bf2f(b1.w)};
  float s=0.f, q=0.f;
  #pragma unroll
  for(int j=0;j<8;j++){ s += v[j]; q += v[j]*v[j]; }
  #pragma unroll
  for(int mask=1;mask<64;mask<<=1){ s += __shfl_xor(s,mask); q += __shfl_xor(q,mask); }
  const float mu  = s*(1.f/512.f);
  const float var = q*(1.f/512.f) - mu*mu;
  const float rstd = rsqrtf(var + 1e-5f);
  float y[8]; float nq = 0.f;
  #pragma unroll
  for(int j=0;j<8;j++){
    const int c = l*8+j;
    y[j] = (v[j]-mu)*rstd*gg[c] + bvec[c];
    nq += y[j]*y[j];
  }
  u16 hv[8];
  #pragma unroll
  for(int j=0;j<8;j++){ hv[j]=f2bf(y[j]); }
  ushort4 hh0={hv[0],hv[1],hv[2],hv[3]}, hh1={hv[4],hv[5],hv[6],hv[7]};
  *(ushort4*)(yh+base)=hh0; *(ushort4*)(yh+base+4)=hh1;
  if(norms){
    #pragma unroll
    for(int mask=1;mask<64;mask<<=1) nq += __shfl_xor(nq,mask);
    if(l==0) norms[rrow] = sqrtf(nq);
  }
}

// ---------------- norm-softmax pooling, stage 1 (bf16 x2) ----------------
__global__ __launch_bounds__(256) void k_pool2(const u16* __restrict__ x2,
   const float* __restrict__ norms, float* __restrict__ partial)
{
  const int b = blockIdx.y, tc = blockIdx.z;
  const int col = blockIdx.x*256 + threadIdx.x;
  __shared__ float wsm[1024];
  __shared__ float red[4];
  const int tid = threadIdx.x, w = tid>>6, l = tid&63;
  float lm = -1e30f;
  for(int i=tid;i<1024;i+=256){ const float n = norms[b*1024+i]; wsm[i]=n; lm=fmaxf(lm,n); }
  #pragma unroll
  for(int mask=1;mask<64;mask<<=1) lm = fmaxf(lm, __shfl_xor(lm,mask));
  __syncthreads();
  if(l==0) red[w]=lm;
  __syncthreads();
  const float bm = fmaxf(fmaxf(red[0],red[1]), fmaxf(red[2],red[3]));
  __syncthreads();
  float ls = 0.f;
  for(int i=tid;i<1024;i+=256){ const float e = __expf(wsm[i]-bm); wsm[i]=e; ls+=e; }
  #pragma unroll
  for(int mask=1;mask<64;mask<<=1) ls += __shfl_xor(ls,mask);
  __syncthreads();
  if(l==0) red[w]=ls;
  __syncthreads();
  const float inv = 1.f/(red[0]+red[1]+red[2]+red[3]);
  float acc = 0.f;
  const int t0 = tc*128;
  for(int t=t0;t<t0+128;t++) acc += wsm[t]*bf2f(x2[((long)b*1024+t)*512 + col]);
  partial[((long)tc*16 + b)*512 + col] = acc*inv;
}

// ---------------- pooling, stage 2: fold 8 partials ----------------
__global__ __launch_bounds__(256) void k_poolr(const float* __restrict__ partial,
   float* __restrict__ pooled)
{
  const int i = blockIdx.x*256 + threadIdx.x;   // 8192 outputs
  float a = 0.f;
  #pragma unroll
  for(int tc=0;tc<8;tc++) a += partial[tc*8192 + i];
  pooled[i] = a;
}

// ---------------- classifier head (tiny) ----------------
__global__ __launch_bounds__(256) void k_head(const float* __restrict__ pooled,
  const float* __restrict__ w1, const float* __restrict__ b1,
  const float* __restrict__ w2, const float* __restrict__ b2,
  float* __restrict__ out)
{
  __shared__ float ps[16*512];
  __shared__ float h1[16*256];
  const int tid = threadIdx.x;
  for(int i=tid;i<16*512;i+=256) ps[i]=pooled[i];
  __syncthreads();
  float acc[16] = {};
  for(int k=0;k<512;k++){
    const float wv = w1[tid*512+k];
    #pragma unroll
    for(int i=0;i<16;i++) acc[i] += ps[i*512+k]*wv;
  }
  #pragma unroll
  for(int i=0;i<16;i++) h1[i*256+tid] = fmaxf(acc[i]+b1[tid], 0.f);
  __syncthreads();
  if(tid<32){
    const int i = tid>>1, o = tid&1;
    float a = b2[o];
    for(int k=0;k<256;k++) a += h1[i*256+k]*w2[o*256+k];
    out[i*2+o] = a;
  }
}

extern "C" void kernel_launch(void* const* d_in, const int* in_sizes, int n_in,
                              void* d_out, int out_size, void* d_ws, size_t ws_size,
                              hipStream_t stream)
{
  const float* trg  = (const float*)d_in[0];
  const float* src  = (const float*)d_in[1];
  const float* ln_g = (const float*)d_in[2];
  const float* ln_b = (const float*)d_in[3];
  const float* wq   = (const float*)d_in[4];  const float* bq  = (const float*)d_in[5];
  const float* wk   = (const float*)d_in[6];  const float* bk  = (const float*)d_in[7];
  const float* wv   = (const float*)d_in[8];  const float* bv  = (const float*)d_in[9];
  const float* wo   = (const float*)d_in[10]; const float* bo  = (const float*)d_in[11];
  const float* pf1w = (const float*)d_in[12]; const float* pf1b= (const float*)d_in[13];
  const float* pf2w = (const float*)d_in[14]; const float* pf2b= (const float*)d_in[15];
  const float* fc1w = (const float*)d_in[16]; const float* fc1b= (const float*)d_in[17];
  const float* fc2w = (const float*)d_in[18]; const float* fc2b= (const float*)d_in[19];
  float* out = (float*)d_out;

  // ---- workspace: 7 bf16 planes (112 MiB) + ~9 MiB weights/misc ----
  // liveness: split8{W:4,5,wts} qkv{R:4,5 W:0,1,2} attn{R:0,1,2 W:3} wo{R:3 W:4}
  //           LN1{R:trg,4 W:5} ff1{R:5 W:0-3} ff2{R:0-3 W:4} LN2{R:5,4 W:6} pool{R:6}
  char* ws = (char*)d_ws;
  const size_t PL = (size_t)16384*512*2;          // one bf16 plane (16 MiB)
  auto P = [&](int i)->u16*{ return (u16*)(ws + (size_t)i*PL); };
  u16 *Qb=P(0), *Kb=P(1), *Vt=P(2), *ctx=P(3);
  u16 *trg_hi=P(4), *src_hi=P(5);                 // dead after qkv
  u16 *sa_bf = P(4);                              // wo out (over trg_hi), LN1 in
  u16 *x1_hi = P(5);                              // LN1 out (over src_hi); ff1 + LN2-residual in
  u16 *h_hi  = P(0);                              // planes 0-3 (64 MiB, over Q/K/V/ctx)
  u16 *ffb_bf= P(4);                              // ff2 out (over sa, dead after LN1)
  u16 *x2_bf = P(6);                              // LN2 out
  size_t off = 7*PL;
  auto carve = [&](size_t n)->char*{ char* p = ws+off; off += n; return p; };
  u16* wqkv_hi=(u16*)carve((size_t)1536*512*2);
  u16* wo_hi=(u16*)carve(512*512*2);
  u16* p1_hi=(u16*)carve((size_t)2048*512*2);
  u16* p2_hi=(u16*)carve((size_t)512*2048*2);
  float* norms  = (float*)carve(16384*4);
  float* partial= (float*)carve(8*16*512*4);
  float* pooled = (float*)carve(16*512*4);
  (void)ws_size; (void)in_sizes; (void)n_in; (void)out_size;

  const int NTOK = 16384;

  // all splits in one launch (8 slots)
  Split8 sp;
  sp.s[0]=trg;  sp.d[0]=trg_hi;           sp.n[0]=NTOK*512;
  sp.s[1]=src;  sp.d[1]=src_hi;           sp.n[1]=NTOK*512;
  sp.s[2]=wq;   sp.d[2]=wqkv_hi;          sp.n[2]=512*512;
  sp.s[3]=wk;   sp.d[3]=wqkv_hi+512*512;  sp.n[3]=512*512;
  sp.s[4]=wv;   sp.d[4]=wqkv_hi+1024*512; sp.n[4]=512*512;
  sp.s[5]=wo;   sp.d[5]=wo_hi;            sp.n[5]=512*512;
  sp.s[6]=pf1w; sp.d[6]=p1_hi;            sp.n[6]=2048*512;
  sp.s[7]=pf2w; sp.d[7]=p2_hi;            sp.n[7]=512*2048;
  k_split8<<<dim3(1024,8),256,0,stream>>>(sp);

  // fused QKV projection (8-wave BK=64, 32x32 MFMA)
  k_qkv<<<dim3(1536),512,0,stream>>>(trg_hi,src_hi,wqkv_hi,bq,bk,bv,Qb,Kb,Vt);

  // attention (QBLK=128, 8 waves, shared single-buffer K/V)
  k_attn<<<dim3(1024),512,0,stream>>>(Qb,Kb,Vt,ctx);

  // output projection (bf16 out) + LN1 (bf16 out only)
  k_gemm<1><<<dim3(4,128),512,0,stream>>>(ctx,wo_hi,bo,NTOK,512,512,nullptr,sa_bf);
  k_ln<1><<<dim3(4096),256,0,stream>>>(trg, nullptr, sa_bf, ln_g, ln_b, x1_hi, nullptr);

  // FFN + LN2 (+ row norms); all bf16 intermediates
  k_gemm<2><<<dim3(16,128),512,0,stream>>>(x1_hi,p1_hi,pf1b,NTOK,2048,512,nullptr,h_hi);
  k_gemm<1><<<dim3(4,128),512,0,stream>>>(h_hi,p2_hi,pf2b,NTOK,512,2048,nullptr,ffb_bf);
  k_ln<0><<<dim3(4096),256,0,stream>>>(nullptr, x1_hi, ffb_bf, ln_g, ln_b, x2_bf, norms);

  // pooling (parallel 2-stage) + head
  k_pool2<<<dim3(2,16,8),256,0,stream>>>(x2_bf, norms, partial);
  k_poolr<<<dim3(32),256,0,stream>>>(partial, pooled);
  k_head<<<1,256,0,stream>>>(pooled, fc1w, fc1b, fc2w, fc2b, out);
}